// Round 1
// 505.849 us; speedup vs baseline: 1.0558x; 1.0558x over previous
//
#include <hip/hip_runtime.h>

#define HID 128

typedef __attribute__((ext_vector_type(8))) short bf16x8;
typedef __attribute__((ext_vector_type(4))) float f32x4;

__device__ inline unsigned short f2bf(float f) {
    unsigned u = __float_as_uint(f);
    unsigned r = (u + 0x7fff + ((u >> 16) & 1)) >> 16;
    return (unsigned short)r;
}
__device__ inline float bf2f(unsigned short b) {
    return __uint_as_float(((unsigned)b) << 16);
}
// split v into trunc-bf16 hi (low 16 bits) + trunc-bf16 lo (high 16 bits)
__device__ inline unsigned packhl(float v) {
    unsigned h = __float_as_uint(v) >> 16;
    float lo = v - __uint_as_float(h << 16);
    unsigned l = __float_as_uint(lo) >> 16;
    return h | (l << 16);
}

// ================= CSR build =================
__global__ void hist_kernel(const int* __restrict__ dst, int* __restrict__ cnt, int E)
{
    int e = blockIdx.x * blockDim.x + threadIdx.x;
    if (e < E) atomicAdd(&cnt[dst[e]], 1);
}

__global__ void scan_block(const int* __restrict__ cnt, int* __restrict__ excl,
                           int* __restrict__ partials, int Nn)
{
    __shared__ int ls[256];
    int i = blockIdx.x * 256 + threadIdx.x;
    int v = (i < Nn) ? cnt[i] : 0;
    ls[threadIdx.x] = v;
    __syncthreads();
    for (int off = 1; off < 256; off <<= 1) {
        int t = (threadIdx.x >= off) ? ls[threadIdx.x - off] : 0;
        __syncthreads();
        ls[threadIdx.x] += t;
        __syncthreads();
    }
    if (i < Nn) excl[i] = ls[threadIdx.x] - v;
    if (threadIdx.x == 255) partials[blockIdx.x] = ls[255];
}

__global__ void scan_partials(int* __restrict__ partials, int nb, int* __restrict__ offsets,
                              int Nn, int E)
{
    __shared__ int ls[256];
    int t = threadIdx.x;
    int v = (t < nb) ? partials[t] : 0;
    ls[t] = v;
    __syncthreads();
    for (int off = 1; off < 256; off <<= 1) {
        int x = (t >= off) ? ls[t - off] : 0;
        __syncthreads();
        ls[t] += x;
        __syncthreads();
    }
    if (t < nb) partials[t] = ls[t] - v;
    if (t == 0) offsets[Nn] = E;
}

__global__ void scan_add(const int* __restrict__ excl, const int* __restrict__ partials,
                         int* __restrict__ offsets, int* __restrict__ cursor, int Nn)
{
    int i = blockIdx.x * 256 + threadIdx.x;
    if (i < Nn) {
        int o = excl[i] + partials[blockIdx.x];
        offsets[i] = o;
        cursor[i] = o;
    }
}

__global__ void fill_kernel(const int* __restrict__ dst, const int* __restrict__ src,
                            const float* __restrict__ ea, int* __restrict__ cursor,
                            float4* __restrict__ epack, int E)
{
    int e = blockIdx.x * blockDim.x + threadIdx.x;
    if (e < E) {
        int pos = atomicAdd(&cursor[dst[e]], 1);
        float4 p;
        p.x = __int_as_float(src[e]);
        p.y = ea[e * 3];
        p.z = ea[e * 3 + 1];
        p.w = ea[e * 3 + 2];
        epack[pos] = p;
    }
}

// ======= W precompute (all 5 matrices in one launch): transpose + hi/lo bf16 split =======
__global__ void wsplit_all(const float* __restrict__ W12, const float* __restrict__ W21,
                           const float* __restrict__ W22, const float* __restrict__ W31,
                           const float* __restrict__ W32, unsigned short* __restrict__ wt)
{
    int w = blockIdx.x >> 6;                     // 64 blocks per matrix
    int idx = (blockIdx.x & 63) * 256 + threadIdx.x;
    const float* W = (w == 0) ? W12 : (w == 1) ? W21 : (w == 2) ? W22 : (w == 3) ? W31 : W32;
    unsigned short* wh = wt + (size_t)w * 32768;
    unsigned short* wl = wh + 16384;
    int n = idx >> 7, k = idx & 127;
    float wv = W[k * 128 + n];
    unsigned short h = (unsigned short)(__float_as_uint(wv) >> 16);
    float lo = wv - bf2f(h);
    unsigned short l = (unsigned short)(__float_as_uint(lo) >> 16);
    wh[idx] = h;
    wl[idx] = l;
}

// ================= layer 1: CSR gather (dim 7) =================
__global__ void gather_d7(const float* __restrict__ x, const float4* __restrict__ epack,
                          const int* __restrict__ offsets,
                          const float* __restrict__ We, const float* __restrict__ be,
                          float* __restrict__ agg, int Nn)
{
    int tid = blockIdx.x * blockDim.x + threadIdx.x;
    int node = tid >> 3;
    int c = tid & 7;
    if (node >= Nn) return;
    float w0 = 0.f, w1 = 0.f, w2 = 0.f, b = 0.f;
    if (c < 7) { w0 = We[c]; w1 = We[7 + c]; w2 = We[14 + c]; b = be[c]; }
    int beg = offsets[node], end = offsets[node + 1];
    float acc = 0.f;
    for (int i = beg; i < end; ++i) {
        float4 ep = epack[i];
        int s = __float_as_int(ep.x);
        float v = b;
        v = fmaf(ep.y, w0, v);
        v = fmaf(ep.z, w1, v);
        v = fmaf(ep.w, w2, v);
        if (c < 7) v += x[s * 7 + c];
        acc += fmaxf(v, 0.f);
    }
    if (c < 7) agg[node * 7 + c] = acc;
}

// ====== layers 2/3: gather, 4x unrolled; self term from h16 (bf16); packed agg out ======
__global__ void gather_d128(const unsigned short* __restrict__ h16,
                            const float4* __restrict__ epack,
                            const int* __restrict__ offsets,
                            const float* __restrict__ We, const float* __restrict__ be,
                            unsigned* __restrict__ aggp, int Nn)
{
    int node = blockIdx.x * (blockDim.x >> 6) + (threadIdx.x >> 6);
    if (node >= Nn) return;
    int lane = threadIdx.x & 63;
    int beg = offsets[node], end = offsets[node + 1];
    const float2* W2 = (const float2*)We;
    float2 w0 = W2[lane];
    float2 w1 = W2[64 + lane];
    float2 w2 = W2[128 + lane];
    float2 bb = ((const float2*)be)[lane];
    float accx = 0.f, accy = 0.f;

    int i = beg;
    for (; i + 4 <= end; i += 4) {
        // non-temporal: epack is streamed once; keep L2 for the gathered h16 rows
        f32x4 e0 = __builtin_nontemporal_load((const f32x4*)(epack + i));
        f32x4 e1 = __builtin_nontemporal_load((const f32x4*)(epack + i + 1));
        f32x4 e2 = __builtin_nontemporal_load((const f32x4*)(epack + i + 2));
        f32x4 e3 = __builtin_nontemporal_load((const f32x4*)(epack + i + 3));
        ushort2 p0 = ((const ushort2*)(h16 + (size_t)__float_as_int(e0.x) * HID))[lane];
        ushort2 p1 = ((const ushort2*)(h16 + (size_t)__float_as_int(e1.x) * HID))[lane];
        ushort2 p2 = ((const ushort2*)(h16 + (size_t)__float_as_int(e2.x) * HID))[lane];
        ushort2 p3 = ((const ushort2*)(h16 + (size_t)__float_as_int(e3.x) * HID))[lane];
        float vx, vy;
        vx = bb.x + bf2f(p0.x);
        vx = fmaf(e0.y, w0.x, vx); vx = fmaf(e0.z, w1.x, vx); vx = fmaf(e0.w, w2.x, vx);
        vy = bb.y + bf2f(p0.y);
        vy = fmaf(e0.y, w0.y, vy); vy = fmaf(e0.z, w1.y, vy); vy = fmaf(e0.w, w2.y, vy);
        accx += fmaxf(vx, 0.f); accy += fmaxf(vy, 0.f);
        vx = bb.x + bf2f(p1.x);
        vx = fmaf(e1.y, w0.x, vx); vx = fmaf(e1.z, w1.x, vx); vx = fmaf(e1.w, w2.x, vx);
        vy = bb.y + bf2f(p1.y);
        vy = fmaf(e1.y, w0.y, vy); vy = fmaf(e1.z, w1.y, vy); vy = fmaf(e1.w, w2.y, vy);
        accx += fmaxf(vx, 0.f); accy += fmaxf(vy, 0.f);
        vx = bb.x + bf2f(p2.x);
        vx = fmaf(e2.y, w0.x, vx); vx = fmaf(e2.z, w1.x, vx); vx = fmaf(e2.w, w2.x, vx);
        vy = bb.y + bf2f(p2.y);
        vy = fmaf(e2.y, w0.y, vy); vy = fmaf(e2.z, w1.y, vy); vy = fmaf(e2.w, w2.y, vy);
        accx += fmaxf(vx, 0.f); accy += fmaxf(vy, 0.f);
        vx = bb.x + bf2f(p3.x);
        vx = fmaf(e3.y, w0.x, vx); vx = fmaf(e3.z, w1.x, vx); vx = fmaf(e3.w, w2.x, vx);
        vy = bb.y + bf2f(p3.y);
        vy = fmaf(e3.y, w0.y, vy); vy = fmaf(e3.z, w1.y, vy); vy = fmaf(e3.w, w2.y, vy);
        accx += fmaxf(vx, 0.f); accy += fmaxf(vy, 0.f);
    }
    for (; i < end; ++i) {
        f32x4 ep = __builtin_nontemporal_load((const f32x4*)(epack + i));
        ushort2 hp = ((const ushort2*)(h16 + (size_t)__float_as_int(ep.x) * HID))[lane];
        float vx = bb.x + bf2f(hp.x);
        vx = fmaf(ep.y, w0.x, vx); vx = fmaf(ep.z, w1.x, vx); vx = fmaf(ep.w, w2.x, vx);
        float vy = bb.y + bf2f(hp.y);
        vy = fmaf(ep.y, w0.y, vy); vy = fmaf(ep.z, w1.y, vy); vy = fmaf(ep.w, w2.y, vy);
        accx += fmaxf(vx, 0.f);
        accy += fmaxf(vy, 0.f);
    }
    // self term from bf16 h row (hot in cache — row also gathered by neighbors)
    ushort2 hv = ((const ushort2*)(h16 + (size_t)node * HID))[lane];
    uint2 ov;
    ov.x = packhl(accx + bf2f(hv.x));
    ov.y = packhl(accy + bf2f(hv.y));
    ((uint2*)(aggp + (size_t)node * HID))[lane] = ov;
}

// ===== MFMA core: acc[2][4] = T(64 rows packed hi/lo) @ Wt for this wave's 32 cols =====
__device__ __forceinline__ void mfma_core(
    const unsigned* T,
    const unsigned short* __restrict__ Wh, const unsigned short* __restrict__ Wl,
    const float* __restrict__ bias,
    int wave, int q, int li, f32x4 (&acc)[2][4])
{
    int ctg0 = wave * 2, ctg1 = wave * 2 + 1;
    float b0 = bias[ctg0 * 16 + li];
    float b1v = bias[ctg1 * 16 + li];
#pragma unroll
    for (int rf = 0; rf < 4; ++rf) {
        acc[0][rf][0] = b0;  acc[0][rf][1] = b0;  acc[0][rf][2] = b0;  acc[0][rf][3] = b0;
        acc[1][rf][0] = b1v; acc[1][rf][1] = b1v; acc[1][rf][2] = b1v; acc[1][rf][3] = b1v;
    }
#pragma unroll
    for (int kb = 0; kb < 4; ++kb) {
        int k0 = kb * 32 + q * 8;
        size_t w0off = (size_t)(ctg0 * 16 + li) * HID + k0;
        size_t w1off = (size_t)(ctg1 * 16 + li) * HID + k0;
        bf16x8 bh0 = *(const bf16x8*)(Wh + w0off);
        bf16x8 bl0 = *(const bf16x8*)(Wl + w0off);
        bf16x8 bh1 = *(const bf16x8*)(Wh + w1off);
        bf16x8 bl1 = *(const bf16x8*)(Wl + w1off);
#pragma unroll
        for (int rf = 0; rf < 4; ++rf) {
            const unsigned* Tp = T + (rf * 16 + li) * 132 + k0;
            uint4 pa = *(const uint4*)Tp;
            uint4 pb = *(const uint4*)(Tp + 4);
            unsigned pv[8] = {pa.x, pa.y, pa.z, pa.w, pb.x, pb.y, pb.z, pb.w};
            bf16x8 ah, al;
#pragma unroll
            for (int j = 0; j < 8; ++j) {
                ah[j] = (short)(pv[j] & 0xffffu);
                al[j] = (short)(pv[j] >> 16);
            }
            acc[0][rf] = __builtin_amdgcn_mfma_f32_16x16x32_bf16(ah, bh0, acc[0][rf], 0, 0, 0);
            acc[0][rf] = __builtin_amdgcn_mfma_f32_16x16x32_bf16(ah, bl0, acc[0][rf], 0, 0, 0);
            acc[0][rf] = __builtin_amdgcn_mfma_f32_16x16x32_bf16(al, bh0, acc[0][rf], 0, 0, 0);
            acc[1][rf] = __builtin_amdgcn_mfma_f32_16x16x32_bf16(ah, bh1, acc[1][rf], 0, 0, 0);
            acc[1][rf] = __builtin_amdgcn_mfma_f32_16x16x32_bf16(ah, bl1, acc[1][rf], 0, 0, 0);
            acc[1][rf] = __builtin_amdgcn_mfma_f32_16x16x32_bf16(al, bh1, acc[1][rf], 0, 0, 0);
        }
    }
}

// global epilogue: write C (+optional relu, +optional BN stats via wave-owned cols)
template <bool RELU, bool STATS>
__device__ __forceinline__ void epilogue_global(
    f32x4 (&acc)[2][4], float* __restrict__ C, float* __restrict__ bnsums,
    float* sls, float* slq, int node0, int wave, int q, int li, int t, int N)
{
#pragma unroll
    for (int ct = 0; ct < 2; ++ct) {
        int colb = (wave * 2 + ct) * 16 + li;
        float sv = 0.f, qv = 0.f;
#pragma unroll
        for (int rf = 0; rf < 4; ++rf) {
#pragma unroll
            for (int r = 0; r < 4; ++r) {
                int n = node0 + rf * 16 + q * 4 + r;
                float v = acc[ct][rf][r];
                if (RELU) v = fmaxf(v, 0.f);
                if (n < N) {
                    C[(size_t)n * HID + colb] = v;
                    if (STATS) { sv += v; qv = fmaf(v, v, qv); }
                }
            }
        }
        if (STATS) {
            sv += __shfl_down(sv, 16); sv += __shfl_down(sv, 32);
            qv += __shfl_down(qv, 16); qv += __shfl_down(qv, 32);
            if (q == 0) { sls[colb] = sv; slq[colb] = qv; }   // unique owner per col
        }
    }
    if (STATS) {
        __syncthreads();
        if (t < 128) {
            atomicAdd(&bnsums[t], sls[t]);
            atomicAdd(&bnsums[128 + t], slq[t]);
        }
    }
}

// ===== fused MLP layers 2/3: C = Lin2(relu(Lin1(A))), A already packed hi/lo =====
template <bool RELU, bool STATS>
__global__ __launch_bounds__(256) void mlp128_fused(
    const unsigned* __restrict__ Ap,
    const unsigned short* __restrict__ W1h, const unsigned short* __restrict__ W1l,
    const float* __restrict__ b1,
    const unsigned short* __restrict__ W2h, const unsigned short* __restrict__ W2l,
    const float* __restrict__ b2,
    float* __restrict__ C, float* __restrict__ bnsums, int N)
{
    __shared__ unsigned Ta[64 * 132];
    __shared__ unsigned Tb[64 * 132];
    __shared__ float sls[128], slq[128];
    int t = threadIdx.x;
    int wave = t >> 6, lane = t & 63;
    int q = lane >> 4, li = lane & 15;
    int node0 = blockIdx.x * 64;

    // ---- stage A (already packed): straight uint4 copy global -> padded LDS ----
    {
        const uint4* A4 = (const uint4*)(Ap + (size_t)node0 * HID);
        int rows = N - node0 < 64 ? (N - node0) : 64;
        int limit4 = 32 * rows;
#pragma unroll
        for (int i = 0; i < 8; ++i) {
            int idx = t + i * 256;
            uint4 v = {0u, 0u, 0u, 0u};
            if (idx < limit4) v = A4[idx];
            int row = idx >> 5, c4 = idx & 31;
            *(uint4*)(Ta + row * 132 + c4 * 4) = v;
        }
    }
    __syncthreads();

    // ---- phase 1: Ta @ W1 -> relu -> packed Tb ----
    {
        f32x4 acc[2][4];
        mfma_core(Ta, W1h, W1l, b1, wave, q, li, acc);
#pragma unroll
        for (int ct = 0; ct < 2; ++ct) {
            int colb = (wave * 2 + ct) * 16 + li;
#pragma unroll
            for (int rf = 0; rf < 4; ++rf) {
#pragma unroll
                for (int r = 0; r < 4; ++r) {
                    float v = fmaxf(acc[ct][rf][r], 0.f);
                    Tb[(rf * 16 + q * 4 + r) * 132 + colb] = packhl(v);
                }
            }
        }
    }
    __syncthreads();

    // ---- phase 2: Tb @ W2 -> C (+stats) ----
    {
        f32x4 acc[2][4];
        mfma_core(Tb, W2h, W2l, b2, wave, q, li, acc);
        epilogue_global<RELU, STATS>(acc, C, bnsums, sls, slq, node0, wave, q, li, t, N);
    }
}

// ===== fused MLP layer 1: phase-1 K=7 fp32 vector -> packed Tb, phase-2 MFMA =====
template <bool RELU, bool STATS>
__global__ __launch_bounds__(256) void mlp1_fused(
    const float* __restrict__ x, const float* __restrict__ agg,
    const float* __restrict__ W1, const float* __restrict__ b1,     // [7][128]
    const unsigned short* __restrict__ W2h, const unsigned short* __restrict__ W2l,
    const float* __restrict__ b2,
    float* __restrict__ C, float* __restrict__ bnsums, int N)
{
    __shared__ unsigned Tb[64 * 132];
    __shared__ float sls[128], slq[128];
    int t = threadIdx.x;
    int wave = t >> 6, lane = t & 63;
    int q = lane >> 4, li = lane & 15;
    int node0 = blockIdx.x * 64;

    // phase 1: rows wave*16+li (4 waves cover 64 rows), q covers col-groups of 32
    {
        int row = node0 + wave * 16 + li;
        bool ok = row < N;
        float xa[7];
#pragma unroll
        for (int k = 0; k < 7; ++k) xa[k] = ok ? (x[row * 7 + k] + agg[row * 7 + k]) : 0.f;
        const float4* W14 = (const float4*)W1;
        const float4* b14 = (const float4*)b1;
        unsigned* Trow = Tb + (wave * 16 + li) * 132 + q * 32;
#pragma unroll
        for (int c4 = 0; c4 < 8; ++c4) {
            float4 v = b14[q * 8 + c4];
#pragma unroll
            for (int k = 0; k < 7; ++k) {
                float4 w = W14[k * 32 + q * 8 + c4];
                v.x = fmaf(xa[k], w.x, v.x);
                v.y = fmaf(xa[k], w.y, v.y);
                v.z = fmaf(xa[k], w.z, v.z);
                v.w = fmaf(xa[k], w.w, v.w);
            }
            uint4 pk;
            pk.x = packhl(fmaxf(v.x, 0.f));
            pk.y = packhl(fmaxf(v.y, 0.f));
            pk.z = packhl(fmaxf(v.z, 0.f));
            pk.w = packhl(fmaxf(v.w, 0.f));
            *(uint4*)(Trow + c4 * 4) = pk;
        }
    }
    __syncthreads();

    // phase 2
    {
        f32x4 acc[2][4];
        mfma_core(Tb, W2h, W2l, b2, wave, q, li, acc);
        epilogue_global<RELU, STATS>(acc, C, bnsums, sls, slq, node0, wave, q, li, t, N);
    }
}

// ========== BN apply (finalize fused per-block) -> bf16 h16 only ==========
__global__ __launch_bounds__(256) void bn_apply_relu(
    const float* __restrict__ h, const float* __restrict__ sums,
    const float* __restrict__ g, const float* __restrict__ bt,
    unsigned short* __restrict__ h16, int Nn, long long total)
{
    __shared__ float as_[128], bs_[128];
    int t = threadIdx.x;
    if (t < 128) {
        float inv = 1.f / (float)Nn;
        float mu = sums[t] * inv;
        float var = sums[128 + t] * inv - mu * mu;
        float rs = rsqrtf(fmaxf(var, 0.f) + 1e-5f);
        float a = g[t] * rs;
        as_[t] = a;
        bs_[t] = bt[t] - a * mu;
    }
    __syncthreads();
    long long i = ((long long)blockIdx.x * 256 + t) * 2;
    if (i >= total) return;
    int c = (int)(i & 127);
    float2 hv = *(const float2*)(h + i);
    float v0 = fmaxf(fmaf(hv.x, as_[c], bs_[c]), 0.f);
    float v1 = fmaxf(fmaf(hv.y, as_[c + 1], bs_[c + 1]), 0.f);
    unsigned pair = (unsigned)f2bf(v0) | ((unsigned)f2bf(v1) << 16);
    *(unsigned*)(h16 + i) = pair;
}

// ===== layer-3 BN-apply + mean-pool: segmented (batch is sorted), finalize fused =====
__global__ __launch_bounds__(256) void bn_pool(
    const float* __restrict__ h, const float* __restrict__ sums,
    const float* __restrict__ g, const float* __restrict__ bt,
    const int* __restrict__ batch,
    float* __restrict__ pools, float* __restrict__ cnt, int Nn)
{
    __shared__ float as_[128], bs_[128];
    int t = threadIdx.x;
    if (t < 128) {
        float inv = 1.f / (float)Nn;
        float mu = sums[t] * inv;
        float var = sums[128 + t] * inv - mu * mu;
        float rs = rsqrtf(fmaxf(var, 0.f) + 1e-5f);
        float a = g[t] * rs;
        as_[t] = a;
        bs_[t] = bt[t] - a * mu;
    }
    __syncthreads();
    int half = t >> 7;                  // waves 0-1 vs 2-3: independent 32-node runs
    int c = t & 127;
    int base = blockIdx.x * 64 + half * 32;
    if (base >= Nn) return;
    int lim = base + 32 < Nn ? base + 32 : Nn;
    int g0 = batch[base];
    float s = 0.f, ncnt = 0.f;
    for (int n = base; n < lim; ++n) {
        int gg = batch[n];              // uniform per half -> broadcast, uniform branch
        if (gg != g0) {
            atomicAdd(&pools[(size_t)g0 * HID + c], s);
            if (c == 0) atomicAdd(&cnt[g0], ncnt);
            s = 0.f; ncnt = 0.f; g0 = gg;
        }
        float v = fmaxf(fmaf(h[(size_t)n * HID + c], as_[c], bs_[c]), 0.f);
        s += v;
        ncnt += 1.f;
    }
    atomicAdd(&pools[(size_t)g0 * HID + c], s);
    if (c == 0) atomicAdd(&cnt[g0], ncnt);
}

__global__ void head_kernel(const float* __restrict__ pools, const float* __restrict__ cnt,
                            const float* __restrict__ Wf1, const float* __restrict__ bf1,
                            const float* __restrict__ Wf2, const float* __restrict__ bf2,
                            float* __restrict__ out, int G)
{
    int g = blockIdx.x;
    int t = threadIdx.x;
    __shared__ float p[128];
    float inv = 1.f / fmaxf(cnt[g], 1.f);
    p[t] = pools[g * 128 + t] * inv;
    p[t + 64] = pools[g * 128 + t + 64] * inv;
    __syncthreads();
    float o = bf1[t];
#pragma unroll 8
    for (int k = 0; k < 128; ++k) o = fmaf(p[k], Wf1[k * 64 + t], o);
    o = fmaxf(o, 0.f);
    float prod = o * Wf2[t];
#pragma unroll
    for (int off = 32; off > 0; off >>= 1) prod += __shfl_down(prod, off);
    if (t == 0) out[g] = prod + bf2[0];
}

extern "C" void kernel_launch(void* const* d_in, const int* in_sizes, int n_in,
                              void* d_out, int out_size, void* d_ws, size_t ws_size,
                              hipStream_t stream)
{
    const float* x     = (const float*)d_in[0];
    const float* ea    = (const float*)d_in[1];
    const int*   eidx  = (const int*)d_in[2];
    const int*   batch = (const int*)d_in[3];
    const float* We1 = (const float*)d_in[4];  const float* be1 = (const float*)d_in[5];
    const float* W11 = (const float*)d_in[6];  const float* b11 = (const float*)d_in[7];
    const float* W12 = (const float*)d_in[8];  const float* b12 = (const float*)d_in[9];
    const float* g1  = (const float*)d_in[10]; const float* bt1 = (const float*)d_in[11];
    const float* We2 = (const float*)d_in[12]; const float* be2 = (const float*)d_in[13];
    const float* W21 = (const float*)d_in[14]; const float* b21 = (const float*)d_in[15];
    const float* W22 = (const float*)d_in[16]; const float* b22 = (const float*)d_in[17];
    const float* g2  = (const float*)d_in[18]; const float* bt2 = (const float*)d_in[19];
    const float* We3 = (const float*)d_in[20]; const float* be3 = (const float*)d_in[21];
    const float* W31 = (const float*)d_in[22]; const float* b31 = (const float*)d_in[23];
    const float* W32 = (const float*)d_in[24]; const float* b32 = (const float*)d_in[25];
    const float* g3  = (const float*)d_in[26]; const float* bt3 = (const float*)d_in[27];
    const float* Wf1 = (const float*)d_in[28]; const float* bf1 = (const float*)d_in[29];
    const float* Wf2 = (const float*)d_in[30]; const float* bf2 = (const float*)d_in[31];

    const int N = in_sizes[0] / 7;
    const int E = in_sizes[1] / 3;
    const int G = out_size;
    const int* src = eidx;
    const int* dst = eidx + E;

    float* ws = (float*)d_ws;
    float* buf_t     = ws;                                   // N*128 (pre-BN output)
    unsigned* aggp   = (unsigned*)(buf_t + (size_t)N * HID); // N*128 packed hi/lo agg
    float* agg7      = (float*)(aggp + (size_t)N * HID);     // N*7
    float* bnsums    = agg7 + (size_t)N * 7;                 // 3 x 256
    float* pools     = bnsums + 768;                         // G*128
    float* cntp      = pools + (size_t)G * HID;              // G
    size_t fused     = (size_t)(cntp + G - ws);
    fused = (fused + 3) & ~(size_t)3;                        // 16B align for epack
    float4* epack    = (float4*)(ws + fused);                // E float4
    unsigned short* h16 = (unsigned short*)(epack + E);      // N*128 bf16
    int*   icnt      = (int*)(h16 + (size_t)N * HID);        // N
    int*   ioffs     = icnt + N;                             // N+1
    int*   icur      = ioffs + N + 1;                        // N
    int*   ipart     = icur + N;                             // 256
    int*   iexcl     = ipart + 256;                          // N
    unsigned short* wt = (unsigned short*)(iexcl + N);       // 5 x 2 x 16384
    unsigned short* w12h = wt;            unsigned short* w12l = wt + 16384;
    unsigned short* w21h = wt + 32768;    unsigned short* w21l = wt + 49152;
    unsigned short* w22h = wt + 65536;    unsigned short* w22l = wt + 81920;
    unsigned short* w31h = wt + 98304;    unsigned short* w31l = wt + 114688;
    unsigned short* w32h = wt + 131072;   unsigned short* w32l = wt + 147456;

    const long long NH = (long long)N * HID;
    const int blk = 256;
    const unsigned grid_nh2  = (unsigned)((NH / 2 + blk - 1) / blk);
    const unsigned grid_mfma = (unsigned)((N + 63) / 64);
    const unsigned grid_E    = (unsigned)((E + blk - 1) / blk);
    const unsigned nb_scan   = (unsigned)((N + 255) / 256);
    const unsigned grid_gather = (unsigned)((N + 3) / 4);
    const unsigned grid_gat7 = (unsigned)(((long long)N * 8 + blk - 1) / blk);
    const unsigned grid_pool = (unsigned)((N + 63) / 64);

    // ---------- W splits (one launch) + bnsums zero (all 3 layers at once) ----------
    wsplit_all<<<320, 256, 0, stream>>>(W12, W21, W22, W31, W32, wt);
    hipMemsetAsync(bnsums, 0, 768 * sizeof(float), stream);

    // ---------- build CSR with packed edges ----------
    hipMemsetAsync(icnt, 0, (size_t)N * sizeof(int), stream);
    hist_kernel<<<grid_E, blk, 0, stream>>>(dst, icnt, E);
    scan_block<<<nb_scan, 256, 0, stream>>>(icnt, iexcl, ipart, N);
    scan_partials<<<1, 256, 0, stream>>>(ipart, nb_scan, ioffs, N, E);
    scan_add<<<nb_scan, 256, 0, stream>>>(iexcl, ipart, ioffs, icur, N);
    fill_kernel<<<grid_E, blk, 0, stream>>>(dst, src, ea, icur, epack, E);

    // ---------- layer 1 ----------
    gather_d7<<<grid_gat7, blk, 0, stream>>>(x, epack, ioffs, We1, be1, agg7, N);
    mlp1_fused<false, true><<<grid_mfma, 256, 0, stream>>>(x, agg7, W11, b11, w12h, w12l, b12, buf_t, bnsums, N);
    bn_apply_relu<<<grid_nh2, blk, 0, stream>>>(buf_t, bnsums, g1, bt1, h16, N, NH);

    // ---------- layer 2 ----------
    gather_d128<<<grid_gather, 256, 0, stream>>>(h16, epack, ioffs, We2, be2, aggp, N);
    mlp128_fused<false, true><<<grid_mfma, 256, 0, stream>>>(aggp, w21h, w21l, b21, w22h, w22l, b22, buf_t, bnsums + 256, N);
    bn_apply_relu<<<grid_nh2, blk, 0, stream>>>(buf_t, bnsums + 256, g2, bt2, h16, N, NH);

    // ---------- layer 3 ----------
    gather_d128<<<grid_gather, 256, 0, stream>>>(h16, epack, ioffs, We3, be3, aggp, N);
    mlp128_fused<false, true><<<grid_mfma, 256, 0, stream>>>(aggp, w31h, w31l, b31, w32h, w32l, b32, buf_t, bnsums + 512, N);

    // ---------- fused BN-apply + segmented pool, then head ----------
    hipMemsetAsync(pools, 0, ((size_t)G * HID + G) * sizeof(float), stream);
    bn_pool<<<grid_pool, 256, 0, stream>>>(buf_t, bnsums + 512, g3, bt3, batch, pools, cntp, N);
    head_kernel<<<G, 64, 0, stream>>>(pools, cntp, Wf1, bf1, Wf2, bf2, (float*)d_out, G);
}

// Round 2
// 459.339 us; speedup vs baseline: 1.1627x; 1.1013x over previous
//
#include <hip/hip_runtime.h>

#define HID 128

typedef __attribute__((ext_vector_type(8))) short bf16x8;
typedef __attribute__((ext_vector_type(4))) float f32x4;

__device__ inline unsigned short f2bf(float f) {
    unsigned u = __float_as_uint(f);
    unsigned r = (u + 0x7fff + ((u >> 16) & 1)) >> 16;
    return (unsigned short)r;
}
__device__ inline float bf2f(unsigned short b) {
    return __uint_as_float(((unsigned)b) << 16);
}
// split v into trunc-bf16 hi (low 16 bits) + trunc-bf16 lo (high 16 bits)
__device__ inline unsigned packhl(float v) {
    unsigned h = __float_as_uint(v) >> 16;
    float lo = v - __uint_as_float(h << 16);
    unsigned l = __float_as_uint(lo) >> 16;
    return h | (l << 16);
}

// ================= CSR build =================
__global__ void hist_kernel(const int* __restrict__ dst, int* __restrict__ cnt, int E)
{
    int e = blockIdx.x * blockDim.x + threadIdx.x;
    if (e < E) atomicAdd(&cnt[dst[e]], 1);
}

__global__ void scan_block(const int* __restrict__ cnt, int* __restrict__ excl,
                           int* __restrict__ partials, int Nn)
{
    __shared__ int ls[256];
    int i = blockIdx.x * 256 + threadIdx.x;
    int v = (i < Nn) ? cnt[i] : 0;
    ls[threadIdx.x] = v;
    __syncthreads();
    for (int off = 1; off < 256; off <<= 1) {
        int t = (threadIdx.x >= off) ? ls[threadIdx.x - off] : 0;
        __syncthreads();
        ls[threadIdx.x] += t;
        __syncthreads();
    }
    if (i < Nn) excl[i] = ls[threadIdx.x] - v;
    if (threadIdx.x == 255) partials[blockIdx.x] = ls[255];
}

__global__ void scan_partials(int* __restrict__ partials, int nb, int* __restrict__ offsets,
                              int Nn, int E)
{
    __shared__ int ls[256];
    int t = threadIdx.x;
    int v = (t < nb) ? partials[t] : 0;
    ls[t] = v;
    __syncthreads();
    for (int off = 1; off < 256; off <<= 1) {
        int x = (t >= off) ? ls[t - off] : 0;
        __syncthreads();
        ls[t] += x;
        __syncthreads();
    }
    if (t < nb) partials[t] = ls[t] - v;
    if (t == 0) offsets[Nn] = E;
}

__global__ void scan_add(const int* __restrict__ excl, const int* __restrict__ partials,
                         int* __restrict__ offsets, int* __restrict__ cursor, int Nn)
{
    int i = blockIdx.x * 256 + threadIdx.x;
    if (i < Nn) {
        int o = excl[i] + partials[blockIdx.x];
        offsets[i] = o;
        cursor[i] = o;
    }
}

__global__ void fill_kernel(const int* __restrict__ dst, const int* __restrict__ src,
                            const float* __restrict__ ea, int* __restrict__ cursor,
                            float4* __restrict__ epack, int E)
{
    int e = blockIdx.x * blockDim.x + threadIdx.x;
    if (e < E) {
        int pos = atomicAdd(&cursor[dst[e]], 1);
        float4 p;
        p.x = __int_as_float(src[e]);
        p.y = ea[e * 3];
        p.z = ea[e * 3 + 1];
        p.w = ea[e * 3 + 2];
        epack[pos] = p;
    }
}

// ======= W precompute (all 5 matrices in one launch): transpose + hi/lo bf16 split =======
__global__ void wsplit_all(const float* __restrict__ W12, const float* __restrict__ W21,
                           const float* __restrict__ W22, const float* __restrict__ W31,
                           const float* __restrict__ W32, unsigned short* __restrict__ wt)
{
    int w = blockIdx.x >> 6;                     // 64 blocks per matrix
    int idx = (blockIdx.x & 63) * 256 + threadIdx.x;
    const float* W = (w == 0) ? W12 : (w == 1) ? W21 : (w == 2) ? W22 : (w == 3) ? W31 : W32;
    unsigned short* wh = wt + (size_t)w * 32768;
    unsigned short* wl = wh + 16384;
    int n = idx >> 7, k = idx & 127;
    float wv = W[k * 128 + n];
    unsigned short h = (unsigned short)(__float_as_uint(wv) >> 16);
    float lo = wv - bf2f(h);
    unsigned short l = (unsigned short)(__float_as_uint(lo) >> 16);
    wh[idx] = h;
    wl[idx] = l;
}

// ================= layer 1: CSR gather (dim 7), 4-deep pipelined =================
__global__ void gather_d7(const float* __restrict__ x, const float4* __restrict__ epack,
                          const int* __restrict__ offsets,
                          const float* __restrict__ We, const float* __restrict__ be,
                          float* __restrict__ agg, int Nn)
{
    int tid = blockIdx.x * blockDim.x + threadIdx.x;
    int node = tid >> 3;
    int c = tid & 7;
    if (node >= Nn) return;
    float w0 = 0.f, w1 = 0.f, w2 = 0.f, b = 0.f;
    if (c < 7) { w0 = We[c]; w1 = We[7 + c]; w2 = We[14 + c]; b = be[c]; }
    int beg = offsets[node], end = offsets[node + 1];
    float acc = 0.f;
    int i = beg;
    for (; i + 4 <= end; i += 4) {
        float4 ep[4]; float xv[4];
#pragma unroll
        for (int j = 0; j < 4; ++j) ep[j] = epack[i + j];
#pragma unroll
        for (int j = 0; j < 4; ++j)
            xv[j] = (c < 7) ? x[__float_as_int(ep[j].x) * 7 + c] : 0.f;
#pragma unroll
        for (int j = 0; j < 4; ++j) {
            float v = b + xv[j];
            v = fmaf(ep[j].y, w0, v);
            v = fmaf(ep[j].z, w1, v);
            v = fmaf(ep[j].w, w2, v);
            acc += fmaxf(v, 0.f);
        }
    }
    int rem = end - i;
    if (rem > 0) {
        float4 ep[4]; float xv[4];
#pragma unroll
        for (int j = 0; j < 4; ++j) if (j < rem) ep[j] = epack[i + j];
#pragma unroll
        for (int j = 0; j < 4; ++j) if (j < rem)
            xv[j] = (c < 7) ? x[__float_as_int(ep[j].x) * 7 + c] : 0.f;
#pragma unroll
        for (int j = 0; j < 4; ++j) if (j < rem) {
            float v = b + xv[j];
            v = fmaf(ep[j].y, w0, v);
            v = fmaf(ep[j].z, w1, v);
            v = fmaf(ep[j].w, w2, v);
            acc += fmaxf(v, 0.f);
        }
    }
    if (c < 7) agg[node * 7 + c] = acc;
}

// ====== layers 2/3: gather, 8-deep pipelined; self term from h16; packed agg out ======
__global__ __launch_bounds__(256) void gather_d128(
    const unsigned short* __restrict__ h16,
    const float4* __restrict__ epack,
    const int* __restrict__ offsets,
    const float* __restrict__ We, const float* __restrict__ be,
    unsigned* __restrict__ aggp, int Nn)
{
    int node = blockIdx.x * 4 + (threadIdx.x >> 6);
    if (node >= Nn) return;
    int lane = threadIdx.x & 63;
    int beg = __builtin_amdgcn_readfirstlane(offsets[node]);
    int end = __builtin_amdgcn_readfirstlane(offsets[node + 1]);
    const float2* W2 = (const float2*)We;
    float2 w0 = W2[lane];
    float2 w1 = W2[64 + lane];
    float2 w2 = W2[128 + lane];
    float2 bb = ((const float2*)be)[lane];
    float accx = 0.f, accy = 0.f;

    int i = beg;
    for (; i + 8 <= end; i += 8) {
        float4 e[8];
        ushort2 p[8];
#pragma unroll
        for (int j = 0; j < 8; ++j) e[j] = epack[i + j];
#pragma unroll
        for (int j = 0; j < 8; ++j)
            p[j] = ((const ushort2*)(h16 + (size_t)__float_as_int(e[j].x) * HID))[lane];
#pragma unroll
        for (int j = 0; j < 8; ++j) {
            float vx = bb.x + bf2f(p[j].x);
            vx = fmaf(e[j].y, w0.x, vx); vx = fmaf(e[j].z, w1.x, vx); vx = fmaf(e[j].w, w2.x, vx);
            float vy = bb.y + bf2f(p[j].y);
            vy = fmaf(e[j].y, w0.y, vy); vy = fmaf(e[j].z, w1.y, vy); vy = fmaf(e[j].w, w2.y, vy);
            accx += fmaxf(vx, 0.f);
            accy += fmaxf(vy, 0.f);
        }
    }
    int rem = end - i;        // wave-uniform (scalar) -> cheap s_cbranch predication
    if (rem > 0) {
        float4 e[8];
        ushort2 p[8];
#pragma unroll
        for (int j = 0; j < 8; ++j) if (j < rem) e[j] = epack[i + j];
#pragma unroll
        for (int j = 0; j < 8; ++j) if (j < rem)
            p[j] = ((const ushort2*)(h16 + (size_t)__float_as_int(e[j].x) * HID))[lane];
#pragma unroll
        for (int j = 0; j < 8; ++j) if (j < rem) {
            float vx = bb.x + bf2f(p[j].x);
            vx = fmaf(e[j].y, w0.x, vx); vx = fmaf(e[j].z, w1.x, vx); vx = fmaf(e[j].w, w2.x, vx);
            float vy = bb.y + bf2f(p[j].y);
            vy = fmaf(e[j].y, w0.y, vy); vy = fmaf(e[j].z, w1.y, vy); vy = fmaf(e[j].w, w2.y, vy);
            accx += fmaxf(vx, 0.f);
            accy += fmaxf(vy, 0.f);
        }
    }
    // self term from bf16 h row (hot in cache — row also gathered by neighbors)
    ushort2 hv = ((const ushort2*)(h16 + (size_t)node * HID))[lane];
    uint2 ov;
    ov.x = packhl(accx + bf2f(hv.x));
    ov.y = packhl(accy + bf2f(hv.y));
    ((uint2*)(aggp + (size_t)node * HID))[lane] = ov;
}

// ===== unpack interleaved hi/lo uint pairs into two bf16x8 via v_perm_b32 =====
__device__ __forceinline__ void unpack_hl(const unsigned* Tp, bf16x8& ah, bf16x8& al)
{
    uint4 pa = *(const uint4*)Tp;
    uint4 pb = *(const uint4*)(Tp + 4);
    union { unsigned u[4]; bf16x8 v; } H, L;
    H.u[0] = __builtin_amdgcn_perm(pa.y, pa.x, 0x05040100u);
    L.u[0] = __builtin_amdgcn_perm(pa.y, pa.x, 0x07060302u);
    H.u[1] = __builtin_amdgcn_perm(pa.w, pa.z, 0x05040100u);
    L.u[1] = __builtin_amdgcn_perm(pa.w, pa.z, 0x07060302u);
    H.u[2] = __builtin_amdgcn_perm(pb.y, pb.x, 0x05040100u);
    L.u[2] = __builtin_amdgcn_perm(pb.y, pb.x, 0x07060302u);
    H.u[3] = __builtin_amdgcn_perm(pb.w, pb.z, 0x05040100u);
    L.u[3] = __builtin_amdgcn_perm(pb.w, pb.z, 0x07060302u);
    ah = H.v;
    al = L.v;
}

// ===== MFMA core: acc[2][4] = T(64 rows packed hi/lo) @ Wt for this wave's 32 cols =====
__device__ __forceinline__ void mfma_core(
    const unsigned* T,
    const unsigned short* __restrict__ Wh, const unsigned short* __restrict__ Wl,
    const float* __restrict__ bias,
    int wave, int q, int li, f32x4 (&acc)[2][4])
{
    int ctg0 = wave * 2, ctg1 = wave * 2 + 1;
    float b0 = bias[ctg0 * 16 + li];
    float b1v = bias[ctg1 * 16 + li];
#pragma unroll
    for (int rf = 0; rf < 4; ++rf) {
        acc[0][rf][0] = b0;  acc[0][rf][1] = b0;  acc[0][rf][2] = b0;  acc[0][rf][3] = b0;
        acc[1][rf][0] = b1v; acc[1][rf][1] = b1v; acc[1][rf][2] = b1v; acc[1][rf][3] = b1v;
    }
#pragma unroll
    for (int kb = 0; kb < 4; ++kb) {
        int k0 = kb * 32 + q * 8;
        size_t w0off = (size_t)(ctg0 * 16 + li) * HID + k0;
        size_t w1off = (size_t)(ctg1 * 16 + li) * HID + k0;
        bf16x8 bh0 = *(const bf16x8*)(Wh + w0off);
        bf16x8 bl0 = *(const bf16x8*)(Wl + w0off);
        bf16x8 bh1 = *(const bf16x8*)(Wh + w1off);
        bf16x8 bl1 = *(const bf16x8*)(Wl + w1off);
#pragma unroll
        for (int rf = 0; rf < 4; ++rf) {
            const unsigned* Tp = T + (rf * 16 + li) * 132 + k0;
            bf16x8 ah, al;
            unpack_hl(Tp, ah, al);
            acc[0][rf] = __builtin_amdgcn_mfma_f32_16x16x32_bf16(ah, bh0, acc[0][rf], 0, 0, 0);
            acc[0][rf] = __builtin_amdgcn_mfma_f32_16x16x32_bf16(ah, bl0, acc[0][rf], 0, 0, 0);
            acc[0][rf] = __builtin_amdgcn_mfma_f32_16x16x32_bf16(al, bh0, acc[0][rf], 0, 0, 0);
            acc[1][rf] = __builtin_amdgcn_mfma_f32_16x16x32_bf16(ah, bh1, acc[1][rf], 0, 0, 0);
            acc[1][rf] = __builtin_amdgcn_mfma_f32_16x16x32_bf16(ah, bl1, acc[1][rf], 0, 0, 0);
            acc[1][rf] = __builtin_amdgcn_mfma_f32_16x16x32_bf16(al, bh1, acc[1][rf], 0, 0, 0);
        }
    }
}

// global epilogue: write C (+optional relu, +optional BN stats via wave-owned cols)
template <bool RELU, bool STATS>
__device__ __forceinline__ void epilogue_global(
    f32x4 (&acc)[2][4], float* __restrict__ C, float* __restrict__ bnsums,
    float* sls, float* slq, int node0, int wave, int q, int li, int t, int N)
{
#pragma unroll
    for (int ct = 0; ct < 2; ++ct) {
        int colb = (wave * 2 + ct) * 16 + li;
        float sv = 0.f, qv = 0.f;
#pragma unroll
        for (int rf = 0; rf < 4; ++rf) {
#pragma unroll
            for (int r = 0; r < 4; ++r) {
                int n = node0 + rf * 16 + q * 4 + r;
                float v = acc[ct][rf][r];
                if (RELU) v = fmaxf(v, 0.f);
                if (n < N) {
                    C[(size_t)n * HID + colb] = v;
                    if (STATS) { sv += v; qv = fmaf(v, v, qv); }
                }
            }
        }
        if (STATS) {
            sv += __shfl_down(sv, 16); sv += __shfl_down(sv, 32);
            qv += __shfl_down(qv, 16); qv += __shfl_down(qv, 32);
            if (q == 0) { sls[colb] = sv; slq[colb] = qv; }   // unique owner per col
        }
    }
    if (STATS) {
        __syncthreads();
        if (t < 128) {
            atomicAdd(&bnsums[t], sls[t]);
            atomicAdd(&bnsums[128 + t], slq[t]);
        }
    }
}

// ===== fused MLP layers 2/3: C = Lin2(relu(Lin1(A))), A already packed hi/lo =====
template <bool RELU, bool STATS>
__global__ __launch_bounds__(256) void mlp128_fused(
    const unsigned* __restrict__ Ap,
    const unsigned short* __restrict__ W1h, const unsigned short* __restrict__ W1l,
    const float* __restrict__ b1,
    const unsigned short* __restrict__ W2h, const unsigned short* __restrict__ W2l,
    const float* __restrict__ b2,
    float* __restrict__ C, float* __restrict__ bnsums, int N)
{
    __shared__ unsigned Ta[64 * 132];
    __shared__ unsigned Tb[64 * 132];
    __shared__ float sls[128], slq[128];
    int t = threadIdx.x;
    int wave = t >> 6, lane = t & 63;
    int q = lane >> 4, li = lane & 15;
    int node0 = blockIdx.x * 64;

    // ---- stage A (already packed): straight uint4 copy global -> padded LDS ----
    {
        const uint4* A4 = (const uint4*)(Ap + (size_t)node0 * HID);
        int rows = N - node0 < 64 ? (N - node0) : 64;
        int limit4 = 32 * rows;
#pragma unroll
        for (int i = 0; i < 8; ++i) {
            int idx = t + i * 256;
            uint4 v = {0u, 0u, 0u, 0u};
            if (idx < limit4) v = A4[idx];
            int row = idx >> 5, c4 = idx & 31;
            *(uint4*)(Ta + row * 132 + c4 * 4) = v;
        }
    }
    __syncthreads();

    // ---- phase 1: Ta @ W1 -> relu -> packed Tb ----
    {
        f32x4 acc[2][4];
        mfma_core(Ta, W1h, W1l, b1, wave, q, li, acc);
#pragma unroll
        for (int ct = 0; ct < 2; ++ct) {
            int colb = (wave * 2 + ct) * 16 + li;
#pragma unroll
            for (int rf = 0; rf < 4; ++rf) {
#pragma unroll
                for (int r = 0; r < 4; ++r) {
                    float v = fmaxf(acc[ct][rf][r], 0.f);
                    Tb[(rf * 16 + q * 4 + r) * 132 + colb] = packhl(v);
                }
            }
        }
    }
    __syncthreads();

    // ---- phase 2: Tb @ W2 -> C (+stats) ----
    {
        f32x4 acc[2][4];
        mfma_core(Tb, W2h, W2l, b2, wave, q, li, acc);
        epilogue_global<RELU, STATS>(acc, C, bnsums, sls, slq, node0, wave, q, li, t, N);
    }
}

// ===== fused MLP layer 1: phase-1 K=7 fp32 vector -> packed Tb, phase-2 MFMA =====
template <bool RELU, bool STATS>
__global__ __launch_bounds__(256) void mlp1_fused(
    const float* __restrict__ x, const float* __restrict__ agg,
    const float* __restrict__ W1, const float* __restrict__ b1,     // [7][128]
    const unsigned short* __restrict__ W2h, const unsigned short* __restrict__ W2l,
    const float* __restrict__ b2,
    float* __restrict__ C, float* __restrict__ bnsums, int N)
{
    __shared__ unsigned Tb[64 * 132];
    __shared__ float sls[128], slq[128];
    int t = threadIdx.x;
    int wave = t >> 6, lane = t & 63;
    int q = lane >> 4, li = lane & 15;
    int node0 = blockIdx.x * 64;

    // phase 1: rows wave*16+li (4 waves cover 64 rows), q covers col-groups of 32
    {
        int row = node0 + wave * 16 + li;
        bool ok = row < N;
        float xa[7];
#pragma unroll
        for (int k = 0; k < 7; ++k) xa[k] = ok ? (x[row * 7 + k] + agg[row * 7 + k]) : 0.f;
        const float4* W14 = (const float4*)W1;
        const float4* b14 = (const float4*)b1;
        unsigned* Trow = Tb + (wave * 16 + li) * 132 + q * 32;
#pragma unroll
        for (int c4 = 0; c4 < 8; ++c4) {
            float4 v = b14[q * 8 + c4];
#pragma unroll
            for (int k = 0; k < 7; ++k) {
                float4 w = W14[k * 32 + q * 8 + c4];
                v.x = fmaf(xa[k], w.x, v.x);
                v.y = fmaf(xa[k], w.y, v.y);
                v.z = fmaf(xa[k], w.z, v.z);
                v.w = fmaf(xa[k], w.w, v.w);
            }
            uint4 pk;
            pk.x = packhl(fmaxf(v.x, 0.f));
            pk.y = packhl(fmaxf(v.y, 0.f));
            pk.z = packhl(fmaxf(v.z, 0.f));
            pk.w = packhl(fmaxf(v.w, 0.f));
            *(uint4*)(Trow + c4 * 4) = pk;
        }
    }
    __syncthreads();

    // phase 2
    {
        f32x4 acc[2][4];
        mfma_core(Tb, W2h, W2l, b2, wave, q, li, acc);
        epilogue_global<RELU, STATS>(acc, C, bnsums, sls, slq, node0, wave, q, li, t, N);
    }
}

// ========== BN apply (finalize fused per-block) -> bf16 h16 only ==========
__global__ __launch_bounds__(256) void bn_apply_relu(
    const float* __restrict__ h, const float* __restrict__ sums,
    const float* __restrict__ g, const float* __restrict__ bt,
    unsigned short* __restrict__ h16, int Nn, long long total)
{
    __shared__ float as_[128], bs_[128];
    int t = threadIdx.x;
    if (t < 128) {
        float inv = 1.f / (float)Nn;
        float mu = sums[t] * inv;
        float var = sums[128 + t] * inv - mu * mu;
        float rs = rsqrtf(fmaxf(var, 0.f) + 1e-5f);
        float a = g[t] * rs;
        as_[t] = a;
        bs_[t] = bt[t] - a * mu;
    }
    __syncthreads();
    long long i = ((long long)blockIdx.x * 256 + t) * 2;
    if (i >= total) return;
    int c = (int)(i & 127);
    float2 hv = *(const float2*)(h + i);
    float v0 = fmaxf(fmaf(hv.x, as_[c], bs_[c]), 0.f);
    float v1 = fmaxf(fmaf(hv.y, as_[c + 1], bs_[c + 1]), 0.f);
    unsigned pair = (unsigned)f2bf(v0) | ((unsigned)f2bf(v1) << 16);
    *(unsigned*)(h16 + i) = pair;
}

// ===== layer-3 BN-apply + mean-pool: segmented (batch is sorted), finalize fused =====
__global__ __launch_bounds__(256) void bn_pool(
    const float* __restrict__ h, const float* __restrict__ sums,
    const float* __restrict__ g, const float* __restrict__ bt,
    const int* __restrict__ batch,
    float* __restrict__ pools, float* __restrict__ cnt, int Nn)
{
    __shared__ float as_[128], bs_[128];
    int t = threadIdx.x;
    if (t < 128) {
        float inv = 1.f / (float)Nn;
        float mu = sums[t] * inv;
        float var = sums[128 + t] * inv - mu * mu;
        float rs = rsqrtf(fmaxf(var, 0.f) + 1e-5f);
        float a = g[t] * rs;
        as_[t] = a;
        bs_[t] = bt[t] - a * mu;
    }
    __syncthreads();
    int half = t >> 7;                  // waves 0-1 vs 2-3: independent 32-node runs
    int c = t & 127;
    int base = blockIdx.x * 64 + half * 32;
    if (base >= Nn) return;
    int lim = base + 32 < Nn ? base + 32 : Nn;
    int g0 = batch[base];
    float s = 0.f, ncnt = 0.f;
    for (int n = base; n < lim; ++n) {
        int gg = batch[n];              // uniform per half -> broadcast, uniform branch
        if (gg != g0) {
            atomicAdd(&pools[(size_t)g0 * HID + c], s);
            if (c == 0) atomicAdd(&cnt[g0], ncnt);
            s = 0.f; ncnt = 0.f; g0 = gg;
        }
        float v = fmaxf(fmaf(h[(size_t)n * HID + c], as_[c], bs_[c]), 0.f);
        s += v;
        ncnt += 1.f;
    }
    atomicAdd(&pools[(size_t)g0 * HID + c], s);
    if (c == 0) atomicAdd(&cnt[g0], ncnt);
}

__global__ void head_kernel(const float* __restrict__ pools, const float* __restrict__ cnt,
                            const float* __restrict__ Wf1, const float* __restrict__ bf1,
                            const float* __restrict__ Wf2, const float* __restrict__ bf2,
                            float* __restrict__ out, int G)
{
    int g = blockIdx.x;
    int t = threadIdx.x;
    __shared__ float p[128];
    float inv = 1.f / fmaxf(cnt[g], 1.f);
    p[t] = pools[g * 128 + t] * inv;
    p[t + 64] = pools[g * 128 + t + 64] * inv;
    __syncthreads();
    float o = bf1[t];
#pragma unroll 8
    for (int k = 0; k < 128; ++k) o = fmaf(p[k], Wf1[k * 64 + t], o);
    o = fmaxf(o, 0.f);
    float prod = o * Wf2[t];
#pragma unroll
    for (int off = 32; off > 0; off >>= 1) prod += __shfl_down(prod, off);
    if (t == 0) out[g] = prod + bf2[0];
}

extern "C" void kernel_launch(void* const* d_in, const int* in_sizes, int n_in,
                              void* d_out, int out_size, void* d_ws, size_t ws_size,
                              hipStream_t stream)
{
    const float* x     = (const float*)d_in[0];
    const float* ea    = (const float*)d_in[1];
    const int*   eidx  = (const int*)d_in[2];
    const int*   batch = (const int*)d_in[3];
    const float* We1 = (const float*)d_in[4];  const float* be1 = (const float*)d_in[5];
    const float* W11 = (const float*)d_in[6];  const float* b11 = (const float*)d_in[7];
    const float* W12 = (const float*)d_in[8];  const float* b12 = (const float*)d_in[9];
    const float* g1  = (const float*)d_in[10]; const float* bt1 = (const float*)d_in[11];
    const float* We2 = (const float*)d_in[12]; const float* be2 = (const float*)d_in[13];
    const float* W21 = (const float*)d_in[14]; const float* b21 = (const float*)d_in[15];
    const float* W22 = (const float*)d_in[16]; const float* b22 = (const float*)d_in[17];
    const float* g2  = (const float*)d_in[18]; const float* bt2 = (const float*)d_in[19];
    const float* We3 = (const float*)d_in[20]; const float* be3 = (const float*)d_in[21];
    const float* W31 = (const float*)d_in[22]; const float* b31 = (const float*)d_in[23];
    const float* W32 = (const float*)d_in[24]; const float* b32 = (const float*)d_in[25];
    const float* g3  = (const float*)d_in[26]; const float* bt3 = (const float*)d_in[27];
    const float* Wf1 = (const float*)d_in[28]; const float* bf1 = (const float*)d_in[29];
    const float* Wf2 = (const float*)d_in[30]; const float* bf2 = (const float*)d_in[31];

    const int N = in_sizes[0] / 7;
    const int E = in_sizes[1] / 3;
    const int G = out_size;
    const int* src = eidx;
    const int* dst = eidx + E;

    float* ws = (float*)d_ws;
    float* buf_t     = ws;                                   // N*128 (pre-BN output)
    unsigned* aggp   = (unsigned*)(buf_t + (size_t)N * HID); // N*128 packed hi/lo agg
    float* agg7      = (float*)(aggp + (size_t)N * HID);     // N*7
    float* bnsums    = agg7 + (size_t)N * 7;                 // 3 x 256
    float* pools     = bnsums + 768;                         // G*128
    float* cntp      = pools + (size_t)G * HID;              // G
    size_t fused     = (size_t)(cntp + G - ws);
    fused = (fused + 3) & ~(size_t)3;                        // 16B align for epack
    float4* epack    = (float4*)(ws + fused);                // E float4
    unsigned short* h16 = (unsigned short*)(epack + E);      // N*128 bf16
    int*   icnt      = (int*)(h16 + (size_t)N * HID);        // N
    int*   ioffs     = icnt + N;                             // N+1
    int*   icur      = ioffs + N + 1;                        // N
    int*   ipart     = icur + N;                             // 256
    int*   iexcl     = ipart + 256;                          // N
    unsigned short* wt = (unsigned short*)(iexcl + N);       // 5 x 2 x 16384
    unsigned short* w12h = wt;            unsigned short* w12l = wt + 16384;
    unsigned short* w21h = wt + 32768;    unsigned short* w21l = wt + 49152;
    unsigned short* w22h = wt + 65536;    unsigned short* w22l = wt + 81920;
    unsigned short* w31h = wt + 98304;    unsigned short* w31l = wt + 114688;
    unsigned short* w32h = wt + 131072;   unsigned short* w32l = wt + 147456;

    const long long NH = (long long)N * HID;
    const int blk = 256;
    const unsigned grid_nh2  = (unsigned)((NH / 2 + blk - 1) / blk);
    const unsigned grid_mfma = (unsigned)((N + 63) / 64);
    const unsigned grid_E    = (unsigned)((E + blk - 1) / blk);
    const unsigned nb_scan   = (unsigned)((N + 255) / 256);
    const unsigned grid_gather = (unsigned)((N + 3) / 4);
    const unsigned grid_gat7 = (unsigned)(((long long)N * 8 + blk - 1) / blk);
    const unsigned grid_pool = (unsigned)((N + 63) / 64);

    // ---------- W splits (one launch) + bnsums zero (all 3 layers at once) ----------
    wsplit_all<<<320, 256, 0, stream>>>(W12, W21, W22, W31, W32, wt);
    hipMemsetAsync(bnsums, 0, 768 * sizeof(float), stream);

    // ---------- build CSR with packed edges ----------
    hipMemsetAsync(icnt, 0, (size_t)N * sizeof(int), stream);
    hist_kernel<<<grid_E, blk, 0, stream>>>(dst, icnt, E);
    scan_block<<<nb_scan, 256, 0, stream>>>(icnt, iexcl, ipart, N);
    scan_partials<<<1, 256, 0, stream>>>(ipart, nb_scan, ioffs, N, E);
    scan_add<<<nb_scan, 256, 0, stream>>>(iexcl, ipart, ioffs, icur, N);
    fill_kernel<<<grid_E, blk, 0, stream>>>(dst, src, ea, icur, epack, E);

    // ---------- layer 1 ----------
    gather_d7<<<grid_gat7, blk, 0, stream>>>(x, epack, ioffs, We1, be1, agg7, N);
    mlp1_fused<false, true><<<grid_mfma, 256, 0, stream>>>(x, agg7, W11, b11, w12h, w12l, b12, buf_t, bnsums, N);
    bn_apply_relu<<<grid_nh2, blk, 0, stream>>>(buf_t, bnsums, g1, bt1, h16, N, NH);

    // ---------- layer 2 ----------
    gather_d128<<<grid_gather, 256, 0, stream>>>(h16, epack, ioffs, We2, be2, aggp, N);
    mlp128_fused<false, true><<<grid_mfma, 256, 0, stream>>>(aggp, w21h, w21l, b21, w22h, w22l, b22, buf_t, bnsums + 256, N);
    bn_apply_relu<<<grid_nh2, blk, 0, stream>>>(buf_t, bnsums + 256, g2, bt2, h16, N, NH);

    // ---------- layer 3 ----------
    gather_d128<<<grid_gather, 256, 0, stream>>>(h16, epack, ioffs, We3, be3, aggp, N);
    mlp128_fused<false, true><<<grid_mfma, 256, 0, stream>>>(aggp, w31h, w31l, b31, w32h, w32l, b32, buf_t, bnsums + 512, N);

    // ---------- fused BN-apply + segmented pool, then head ----------
    hipMemsetAsync(pools, 0, ((size_t)G * HID + G) * sizeof(float), stream);
    bn_pool<<<grid_pool, 256, 0, stream>>>(buf_t, bnsums + 512, g3, bt3, batch, pools, cntp, N);
    head_kernel<<<G, 64, 0, stream>>>(pools, cntp, Wf1, bf1, Wf2, bf2, (float*)d_out, G);
}

// Round 3
// 448.410 us; speedup vs baseline: 1.1910x; 1.0244x over previous
//
#include <hip/hip_runtime.h>

#define HID 128
#define CHUNK 3072      // edges per epart block
#define CAP2 5120       // max edges per 256-node bucket in elocal fast path

typedef __attribute__((ext_vector_type(8))) short bf16x8;
typedef __attribute__((ext_vector_type(4))) float f32x4;

__device__ inline unsigned short f2bf(float f) {
    unsigned u = __float_as_uint(f);
    unsigned r = (u + 0x7fff + ((u >> 16) & 1)) >> 16;
    return (unsigned short)r;
}
__device__ inline float bf2f(unsigned short b) {
    return __uint_as_float(((unsigned)b) << 16);
}
// split v into trunc-bf16 hi (low 16 bits) + trunc-bf16 lo (high 16 bits)
__device__ inline unsigned packhl(float v) {
    unsigned h = __float_as_uint(v) >> 16;
    float lo = v - __uint_as_float(h << 16);
    unsigned l = __float_as_uint(lo) >> 16;
    return h | (l << 16);
}

// ================= CSR build =================
__global__ void hist_kernel(const int* __restrict__ dst, int* __restrict__ cnt, int E)
{
    int e = blockIdx.x * blockDim.x + threadIdx.x;
    if (e < E) atomicAdd(&cnt[dst[e]], 1);
}

__global__ void scan_block(const int* __restrict__ cnt, int* __restrict__ excl,
                           int* __restrict__ partials, int Nn)
{
    __shared__ int ls[256];
    int i = blockIdx.x * 256 + threadIdx.x;
    int v = (i < Nn) ? cnt[i] : 0;
    ls[threadIdx.x] = v;
    __syncthreads();
    for (int off = 1; off < 256; off <<= 1) {
        int t = (threadIdx.x >= off) ? ls[threadIdx.x - off] : 0;
        __syncthreads();
        ls[threadIdx.x] += t;
        __syncthreads();
    }
    if (i < Nn) excl[i] = ls[threadIdx.x] - v;
    if (threadIdx.x == 255) partials[blockIdx.x] = ls[255];
}

__global__ void scan_partials(int* __restrict__ partials, int nb, int* __restrict__ offsets,
                              int Nn, int E)
{
    __shared__ int ls[256];
    int t = threadIdx.x;
    int v = (t < nb) ? partials[t] : 0;
    ls[t] = v;
    __syncthreads();
    for (int off = 1; off < 256; off <<= 1) {
        int x = (t >= off) ? ls[t - off] : 0;
        __syncthreads();
        ls[t] += x;
        __syncthreads();
    }
    if (t < nb) partials[t] = ls[t] - v;
    if (t == 0) offsets[Nn] = E;
}

// writes offsets and initializes per-bucket slice cursors bcur[b] = offsets[b*256]
__global__ void scan_add(const int* __restrict__ excl, const int* __restrict__ partials,
                         int* __restrict__ offsets, int* __restrict__ bcur, int Nn)
{
    int i = blockIdx.x * 256 + threadIdx.x;
    if (i < Nn) {
        int o = excl[i] + partials[blockIdx.x];
        offsets[i] = o;
        if ((i & 255) == 0) bcur[i >> 8] = o;
    }
}

// ===== epart: partition edges into 256-node MSD buckets, LDS-staged coalesced writes =====
__global__ __launch_bounds__(256) void epart(
    const int* __restrict__ dst, const int* __restrict__ src,
    const float* __restrict__ ea, int* __restrict__ bcur,
    float4* __restrict__ stage, int* __restrict__ sdst, int E)
{
    __shared__ float4 buf[CHUNK];          // 48KB: payload in locally-sorted order
    __shared__ int    spos[CHUNK];         // 12KB: global dest pos per sorted slot
    __shared__ int    sdl[CHUNK];          // 12KB: dst value per sorted slot
    __shared__ int    cnt[256], gsl[256], exs[256], scw[256];
    int t = threadIdx.x;
    int e0 = blockIdx.x * CHUNK;
    int n = E - e0; if (n > CHUNK) n = CHUNK;
    cnt[t] = 0;
    __syncthreads();
    // trip 1: count per bucket
    for (int k = t; k < n; k += 256) {
        int d = dst[e0 + k] >> 8;
        atomicAdd(&cnt[d], 1);
    }
    __syncthreads();
    int v = cnt[t];
    // reserve contiguous global slice per bucket (one atomic per non-empty digit)
    int gb = 0;
    if (v > 0) gb = atomicAdd(&bcur[t], v);
    gsl[t] = gb;
    // exclusive scan of cnt
    scw[t] = v;
    __syncthreads();
    for (int off = 1; off < 256; off <<= 1) {
        int x = (t >= off) ? scw[t - off] : 0;
        __syncthreads();
        scw[t] += x;
        __syncthreads();
    }
    int excl = scw[t] - v;
    exs[t] = excl;
    cnt[t] = excl;              // becomes fill cursor: slot = excl + local rank
    __syncthreads();
    // trip 2: rank + LDS scatter into sorted order
    for (int k = t; k < n; k += 256) {
        int e = e0 + k;
        int dv = dst[e];
        int d = dv >> 8;
        int s = atomicAdd(&cnt[d], 1);
        float4 p;
        p.x = __int_as_float(src[e]);
        p.y = ea[e * 3];
        p.z = ea[e * 3 + 1];
        p.w = ea[e * 3 + 2];
        buf[s] = p;
        sdl[s] = dv;
        spos[s] = gsl[d] + (s - exs[d]);
    }
    __syncthreads();
    // linear writeout: consecutive slots -> consecutive addresses within each run
    for (int k = t; k < n; k += 256) {
        int pos = spos[k];
        stage[pos] = buf[k];
        sdst[pos] = sdl[k];
    }
}

// ===== elocal: per-bucket counting sort into final CSR epack, coalesced writes =====
__global__ __launch_bounds__(256) void elocal(
    const float4* __restrict__ stage, const int* __restrict__ sdst,
    const int* __restrict__ offsets, float4* __restrict__ epack, int Nn)
{
    __shared__ float4 buf[CAP2];           // 80KB
    __shared__ int    spos[CAP2];          // 20KB
    __shared__ unsigned short ld[CAP2];    // 10KB: local dst (0..255)
    __shared__ int    cnt[256], exs[256], noff[256], scw[256];
    int t = threadIdx.x;
    int b = blockIdx.x;
    int nbeg = b << 8;
    int nend = nbeg + 256; if (nend > Nn) nend = Nn;
    int beg = offsets[nbeg];
    int end = offsets[nend];
    int n = end - beg;
    noff[t] = (nbeg + t < Nn) ? offsets[nbeg + t] : 0;
    cnt[t] = 0;
    __syncthreads();
    if (n <= CAP2) {
        for (int k = t; k < n; k += 256) {
            int d = sdst[beg + k] & 255;
            ld[k] = (unsigned short)d;
            atomicAdd(&cnt[d], 1);
        }
        __syncthreads();
        int v = cnt[t];
        scw[t] = v;
        __syncthreads();
        for (int off = 1; off < 256; off <<= 1) {
            int x = (t >= off) ? scw[t - off] : 0;
            __syncthreads();
            scw[t] += x;
            __syncthreads();
        }
        int excl = scw[t] - v;
        exs[t] = excl;
        cnt[t] = excl;          // fill cursor
        __syncthreads();
        for (int k = t; k < n; k += 256) {
            int d = ld[k];
            int s = atomicAdd(&cnt[d], 1);
            buf[s] = stage[beg + k];
            spos[s] = noff[d] + (s - exs[d]);
        }
        __syncthreads();
        for (int k = t; k < n; k += 256)
            epack[spos[k]] = buf[k];
    } else {
        // fallback (degenerate degree distribution): direct scatter, correct but slow
        for (int k = t; k < n; k += 256) {
            int d = sdst[beg + k] & 255;
            int r = atomicAdd(&cnt[d], 1);
            epack[noff[d] + r] = stage[beg + k];
        }
    }
}

// ======= W precompute (all 5 matrices + bnsums zeroing in one launch) =======
__global__ void wsplit_all(const float* __restrict__ W12, const float* __restrict__ W21,
                           const float* __restrict__ W22, const float* __restrict__ W31,
                           const float* __restrict__ W32, unsigned short* __restrict__ wt,
                           float* __restrict__ bnsums)
{
    if (blockIdx.x == 320) {            // extra block zeroes the 3x256 BN accumulators
        for (int i = threadIdx.x; i < 768; i += 256) bnsums[i] = 0.f;
        return;
    }
    int w = blockIdx.x >> 6;            // 64 blocks per matrix
    int idx = (blockIdx.x & 63) * 256 + threadIdx.x;
    const float* W = (w == 0) ? W12 : (w == 1) ? W21 : (w == 2) ? W22 : (w == 3) ? W31 : W32;
    unsigned short* wh = wt + (size_t)w * 32768;
    unsigned short* wl = wh + 16384;
    int n = idx >> 7, k = idx & 127;
    float wv = W[k * 128 + n];
    unsigned short h = (unsigned short)(__float_as_uint(wv) >> 16);
    float lo = wv - bf2f(h);
    unsigned short l = (unsigned short)(__float_as_uint(lo) >> 16);
    wh[idx] = h;
    wl[idx] = l;
}

// ================= layer 1: CSR gather (dim 7), 4-deep pipelined =================
__global__ void gather_d7(const float* __restrict__ x, const float4* __restrict__ epack,
                          const int* __restrict__ offsets,
                          const float* __restrict__ We, const float* __restrict__ be,
                          float* __restrict__ agg, int Nn)
{
    int tid = blockIdx.x * blockDim.x + threadIdx.x;
    int node = tid >> 3;
    int c = tid & 7;
    if (node >= Nn) return;
    float w0 = 0.f, w1 = 0.f, w2 = 0.f, b = 0.f;
    if (c < 7) { w0 = We[c]; w1 = We[7 + c]; w2 = We[14 + c]; b = be[c]; }
    int beg = offsets[node], end = offsets[node + 1];
    float acc = 0.f;
    int i = beg;
    for (; i + 4 <= end; i += 4) {
        float4 ep[4]; float xv[4];
#pragma unroll
        for (int j = 0; j < 4; ++j) ep[j] = epack[i + j];
#pragma unroll
        for (int j = 0; j < 4; ++j)
            xv[j] = (c < 7) ? x[__float_as_int(ep[j].x) * 7 + c] : 0.f;
#pragma unroll
        for (int j = 0; j < 4; ++j) {
            float v = b + xv[j];
            v = fmaf(ep[j].y, w0, v);
            v = fmaf(ep[j].z, w1, v);
            v = fmaf(ep[j].w, w2, v);
            acc += fmaxf(v, 0.f);
        }
    }
    int rem = end - i;
    if (rem > 0) {
        float4 ep[4]; float xv[4];
#pragma unroll
        for (int j = 0; j < 4; ++j) if (j < rem) ep[j] = epack[i + j];
#pragma unroll
        for (int j = 0; j < 4; ++j) if (j < rem)
            xv[j] = (c < 7) ? x[__float_as_int(ep[j].x) * 7 + c] : 0.f;
#pragma unroll
        for (int j = 0; j < 4; ++j) if (j < rem) {
            float v = b + xv[j];
            v = fmaf(ep[j].y, w0, v);
            v = fmaf(ep[j].z, w1, v);
            v = fmaf(ep[j].w, w2, v);
            acc += fmaxf(v, 0.f);
        }
    }
    if (c < 7) agg[node * 7 + c] = acc;
}

// ====== layers 2/3: gather, 8-deep pipelined; self term from h16; packed agg out ======
__global__ __launch_bounds__(256) void gather_d128(
    const unsigned short* __restrict__ h16,
    const float4* __restrict__ epack,
    const int* __restrict__ offsets,
    const float* __restrict__ We, const float* __restrict__ be,
    unsigned* __restrict__ aggp, int Nn)
{
    int node = blockIdx.x * 4 + (threadIdx.x >> 6);
    if (node >= Nn) return;
    int lane = threadIdx.x & 63;
    int beg = __builtin_amdgcn_readfirstlane(offsets[node]);
    int end = __builtin_amdgcn_readfirstlane(offsets[node + 1]);
    const float2* W2 = (const float2*)We;
    float2 w0 = W2[lane];
    float2 w1 = W2[64 + lane];
    float2 w2 = W2[128 + lane];
    float2 bb = ((const float2*)be)[lane];
    float accx = 0.f, accy = 0.f;

    int i = beg;
    for (; i + 8 <= end; i += 8) {
        float4 e[8];
        ushort2 p[8];
#pragma unroll
        for (int j = 0; j < 8; ++j) e[j] = epack[i + j];
#pragma unroll
        for (int j = 0; j < 8; ++j)
            p[j] = ((const ushort2*)(h16 + (size_t)__float_as_int(e[j].x) * HID))[lane];
#pragma unroll
        for (int j = 0; j < 8; ++j) {
            float vx = bb.x + bf2f(p[j].x);
            vx = fmaf(e[j].y, w0.x, vx); vx = fmaf(e[j].z, w1.x, vx); vx = fmaf(e[j].w, w2.x, vx);
            float vy = bb.y + bf2f(p[j].y);
            vy = fmaf(e[j].y, w0.y, vy); vy = fmaf(e[j].z, w1.y, vy); vy = fmaf(e[j].w, w2.y, vy);
            accx += fmaxf(vx, 0.f);
            accy += fmaxf(vy, 0.f);
        }
    }
    int rem = end - i;        // wave-uniform (scalar) -> cheap s_cbranch predication
    if (rem > 0) {
        float4 e[8];
        ushort2 p[8];
#pragma unroll
        for (int j = 0; j < 8; ++j) if (j < rem) e[j] = epack[i + j];
#pragma unroll
        for (int j = 0; j < 8; ++j) if (j < rem)
            p[j] = ((const ushort2*)(h16 + (size_t)__float_as_int(e[j].x) * HID))[lane];
#pragma unroll
        for (int j = 0; j < 8; ++j) if (j < rem) {
            float vx = bb.x + bf2f(p[j].x);
            vx = fmaf(e[j].y, w0.x, vx); vx = fmaf(e[j].z, w1.x, vx); vx = fmaf(e[j].w, w2.x, vx);
            float vy = bb.y + bf2f(p[j].y);
            vy = fmaf(e[j].y, w0.y, vy); vy = fmaf(e[j].z, w1.y, vy); vy = fmaf(e[j].w, w2.y, vy);
            accx += fmaxf(vx, 0.f);
            accy += fmaxf(vy, 0.f);
        }
    }
    // self term from bf16 h row (hot in cache — row also gathered by neighbors)
    ushort2 hv = ((const ushort2*)(h16 + (size_t)node * HID))[lane];
    uint2 ov;
    ov.x = packhl(accx + bf2f(hv.x));
    ov.y = packhl(accy + bf2f(hv.y));
    ((uint2*)(aggp + (size_t)node * HID))[lane] = ov;
}

// ===== unpack interleaved hi/lo uint pairs into two bf16x8 via v_perm_b32 =====
__device__ __forceinline__ void unpack_hl(const unsigned* Tp, bf16x8& ah, bf16x8& al)
{
    uint4 pa = *(const uint4*)Tp;
    uint4 pb = *(const uint4*)(Tp + 4);
    union { unsigned u[4]; bf16x8 v; } H, L;
    H.u[0] = __builtin_amdgcn_perm(pa.y, pa.x, 0x05040100u);
    L.u[0] = __builtin_amdgcn_perm(pa.y, pa.x, 0x07060302u);
    H.u[1] = __builtin_amdgcn_perm(pa.w, pa.z, 0x05040100u);
    L.u[1] = __builtin_amdgcn_perm(pa.w, pa.z, 0x07060302u);
    H.u[2] = __builtin_amdgcn_perm(pb.y, pb.x, 0x05040100u);
    L.u[2] = __builtin_amdgcn_perm(pb.y, pb.x, 0x07060302u);
    H.u[3] = __builtin_amdgcn_perm(pb.w, pb.z, 0x05040100u);
    L.u[3] = __builtin_amdgcn_perm(pb.w, pb.z, 0x07060302u);
    ah = H.v;
    al = L.v;
}

// ===== MFMA core: acc[2][4] = T(64 rows packed hi/lo) @ Wt for this wave's 32 cols =====
__device__ __forceinline__ void mfma_core(
    const unsigned* T,
    const unsigned short* __restrict__ Wh, const unsigned short* __restrict__ Wl,
    const float* __restrict__ bias,
    int wave, int q, int li, f32x4 (&acc)[2][4])
{
    int ctg0 = wave * 2, ctg1 = wave * 2 + 1;
    float b0 = bias[ctg0 * 16 + li];
    float b1v = bias[ctg1 * 16 + li];
#pragma unroll
    for (int rf = 0; rf < 4; ++rf) {
        acc[0][rf][0] = b0;  acc[0][rf][1] = b0;  acc[0][rf][2] = b0;  acc[0][rf][3] = b0;
        acc[1][rf][0] = b1v; acc[1][rf][1] = b1v; acc[1][rf][2] = b1v; acc[1][rf][3] = b1v;
    }
#pragma unroll
    for (int kb = 0; kb < 4; ++kb) {
        int k0 = kb * 32 + q * 8;
        size_t w0off = (size_t)(ctg0 * 16 + li) * HID + k0;
        size_t w1off = (size_t)(ctg1 * 16 + li) * HID + k0;
        bf16x8 bh0 = *(const bf16x8*)(Wh + w0off);
        bf16x8 bl0 = *(const bf16x8*)(Wl + w0off);
        bf16x8 bh1 = *(const bf16x8*)(Wh + w1off);
        bf16x8 bl1 = *(const bf16x8*)(Wl + w1off);
#pragma unroll
        for (int rf = 0; rf < 4; ++rf) {
            const unsigned* Tp = T + (rf * 16 + li) * 132 + k0;
            bf16x8 ah, al;
            unpack_hl(Tp, ah, al);
            acc[0][rf] = __builtin_amdgcn_mfma_f32_16x16x32_bf16(ah, bh0, acc[0][rf], 0, 0, 0);
            acc[0][rf] = __builtin_amdgcn_mfma_f32_16x16x32_bf16(ah, bl0, acc[0][rf], 0, 0, 0);
            acc[0][rf] = __builtin_amdgcn_mfma_f32_16x16x32_bf16(al, bh0, acc[0][rf], 0, 0, 0);
            acc[1][rf] = __builtin_amdgcn_mfma_f32_16x16x32_bf16(ah, bh1, acc[1][rf], 0, 0, 0);
            acc[1][rf] = __builtin_amdgcn_mfma_f32_16x16x32_bf16(ah, bl1, acc[1][rf], 0, 0, 0);
            acc[1][rf] = __builtin_amdgcn_mfma_f32_16x16x32_bf16(al, bh1, acc[1][rf], 0, 0, 0);
        }
    }
}

// global epilogue: write C (+optional relu, +optional BN stats via wave-owned cols)
template <bool RELU, bool STATS>
__device__ __forceinline__ void epilogue_global(
    f32x4 (&acc)[2][4], float* __restrict__ C, float* __restrict__ bnsums,
    float* sls, float* slq, int node0, int wave, int q, int li, int t, int N)
{
#pragma unroll
    for (int ct = 0; ct < 2; ++ct) {
        int colb = (wave * 2 + ct) * 16 + li;
        float sv = 0.f, qv = 0.f;
#pragma unroll
        for (int rf = 0; rf < 4; ++rf) {
#pragma unroll
            for (int r = 0; r < 4; ++r) {
                int n = node0 + rf * 16 + q * 4 + r;
                float v = acc[ct][rf][r];
                if (RELU) v = fmaxf(v, 0.f);
                if (n < N) {
                    C[(size_t)n * HID + colb] = v;
                    if (STATS) { sv += v; qv = fmaf(v, v, qv); }
                }
            }
        }
        if (STATS) {
            sv += __shfl_down(sv, 16); sv += __shfl_down(sv, 32);
            qv += __shfl_down(qv, 16); qv += __shfl_down(qv, 32);
            if (q == 0) { sls[colb] = sv; slq[colb] = qv; }   // unique owner per col
        }
    }
    if (STATS) {
        __syncthreads();
        if (t < 128) {
            atomicAdd(&bnsums[t], sls[t]);
            atomicAdd(&bnsums[128 + t], slq[t]);
        }
    }
}

// ===== fused MLP layers 2/3: C = Lin2(relu(Lin1(A))), A already packed hi/lo =====
template <bool RELU, bool STATS>
__global__ __launch_bounds__(256) void mlp128_fused(
    const unsigned* __restrict__ Ap,
    const unsigned short* __restrict__ W1h, const unsigned short* __restrict__ W1l,
    const float* __restrict__ b1,
    const unsigned short* __restrict__ W2h, const unsigned short* __restrict__ W2l,
    const float* __restrict__ b2,
    float* __restrict__ C, float* __restrict__ bnsums, int N)
{
    __shared__ unsigned Ta[64 * 132];
    __shared__ unsigned Tb[64 * 132];
    __shared__ float sls[128], slq[128];
    int t = threadIdx.x;
    int wave = t >> 6, lane = t & 63;
    int q = lane >> 4, li = lane & 15;
    int node0 = blockIdx.x * 64;

    // ---- stage A (already packed): straight uint4 copy global -> padded LDS ----
    {
        const uint4* A4 = (const uint4*)(Ap + (size_t)node0 * HID);
        int rows = N - node0 < 64 ? (N - node0) : 64;
        int limit4 = 32 * rows;
#pragma unroll
        for (int i = 0; i < 8; ++i) {
            int idx = t + i * 256;
            uint4 v = {0u, 0u, 0u, 0u};
            if (idx < limit4) v = A4[idx];
            int row = idx >> 5, c4 = idx & 31;
            *(uint4*)(Ta + row * 132 + c4 * 4) = v;
        }
    }
    __syncthreads();

    // ---- phase 1: Ta @ W1 -> relu -> packed Tb ----
    {
        f32x4 acc[2][4];
        mfma_core(Ta, W1h, W1l, b1, wave, q, li, acc);
#pragma unroll
        for (int ct = 0; ct < 2; ++ct) {
            int colb = (wave * 2 + ct) * 16 + li;
#pragma unroll
            for (int rf = 0; rf < 4; ++rf) {
#pragma unroll
                for (int r = 0; r < 4; ++r) {
                    float v = fmaxf(acc[ct][rf][r], 0.f);
                    Tb[(rf * 16 + q * 4 + r) * 132 + colb] = packhl(v);
                }
            }
        }
    }
    __syncthreads();

    // ---- phase 2: Tb @ W2 -> C (+stats) ----
    {
        f32x4 acc[2][4];
        mfma_core(Tb, W2h, W2l, b2, wave, q, li, acc);
        epilogue_global<RELU, STATS>(acc, C, bnsums, sls, slq, node0, wave, q, li, t, N);
    }
}

// ===== fused MLP layer 1: phase-1 K=7 fp32 vector -> packed Tb, phase-2 MFMA =====
template <bool RELU, bool STATS>
__global__ __launch_bounds__(256) void mlp1_fused(
    const float* __restrict__ x, const float* __restrict__ agg,
    const float* __restrict__ W1, const float* __restrict__ b1,     // [7][128]
    const unsigned short* __restrict__ W2h, const unsigned short* __restrict__ W2l,
    const float* __restrict__ b2,
    float* __restrict__ C, float* __restrict__ bnsums, int N)
{
    __shared__ unsigned Tb[64 * 132];
    __shared__ float sls[128], slq[128];
    int t = threadIdx.x;
    int wave = t >> 6, lane = t & 63;
    int q = lane >> 4, li = lane & 15;
    int node0 = blockIdx.x * 64;

    // phase 1: rows wave*16+li (4 waves cover 64 rows), q covers col-groups of 32
    {
        int row = node0 + wave * 16 + li;
        bool ok = row < N;
        float xa[7];
#pragma unroll
        for (int k = 0; k < 7; ++k) xa[k] = ok ? (x[row * 7 + k] + agg[row * 7 + k]) : 0.f;
        const float4* W14 = (const float4*)W1;
        const float4* b14 = (const float4*)b1;
        unsigned* Trow = Tb + (wave * 16 + li) * 132 + q * 32;
#pragma unroll
        for (int c4 = 0; c4 < 8; ++c4) {
            float4 v = b14[q * 8 + c4];
#pragma unroll
            for (int k = 0; k < 7; ++k) {
                float4 w = W14[k * 32 + q * 8 + c4];
                v.x = fmaf(xa[k], w.x, v.x);
                v.y = fmaf(xa[k], w.y, v.y);
                v.z = fmaf(xa[k], w.z, v.z);
                v.w = fmaf(xa[k], w.w, v.w);
            }
            uint4 pk;
            pk.x = packhl(fmaxf(v.x, 0.f));
            pk.y = packhl(fmaxf(v.y, 0.f));
            pk.z = packhl(fmaxf(v.z, 0.f));
            pk.w = packhl(fmaxf(v.w, 0.f));
            *(uint4*)(Trow + c4 * 4) = pk;
        }
    }
    __syncthreads();

    // phase 2
    {
        f32x4 acc[2][4];
        mfma_core(Tb, W2h, W2l, b2, wave, q, li, acc);
        epilogue_global<RELU, STATS>(acc, C, bnsums, sls, slq, node0, wave, q, li, t, N);
    }
}

// ========== BN apply (finalize fused per-block) -> bf16 h16 only ==========
__global__ __launch_bounds__(256) void bn_apply_relu(
    const float* __restrict__ h, const float* __restrict__ sums,
    const float* __restrict__ g, const float* __restrict__ bt,
    unsigned short* __restrict__ h16, int Nn, long long total)
{
    __shared__ float as_[128], bs_[128];
    int t = threadIdx.x;
    if (t < 128) {
        float inv = 1.f / (float)Nn;
        float mu = sums[t] * inv;
        float var = sums[128 + t] * inv - mu * mu;
        float rs = rsqrtf(fmaxf(var, 0.f) + 1e-5f);
        float a = g[t] * rs;
        as_[t] = a;
        bs_[t] = bt[t] - a * mu;
    }
    __syncthreads();
    long long i = ((long long)blockIdx.x * 256 + t) * 2;
    if (i >= total) return;
    int c = (int)(i & 127);
    float2 hv = *(const float2*)(h + i);
    float v0 = fmaxf(fmaf(hv.x, as_[c], bs_[c]), 0.f);
    float v1 = fmaxf(fmaf(hv.y, as_[c + 1], bs_[c + 1]), 0.f);
    unsigned pair = (unsigned)f2bf(v0) | ((unsigned)f2bf(v1) << 16);
    *(unsigned*)(h16 + i) = pair;
}

// ===== layer-3 BN-apply + mean-pool: segmented (batch is sorted), finalize fused =====
__global__ __launch_bounds__(256) void bn_pool(
    const float* __restrict__ h, const float* __restrict__ sums,
    const float* __restrict__ g, const float* __restrict__ bt,
    const int* __restrict__ batch,
    float* __restrict__ pools, float* __restrict__ cnt, int Nn)
{
    __shared__ float as_[128], bs_[128];
    int t = threadIdx.x;
    if (t < 128) {
        float inv = 1.f / (float)Nn;
        float mu = sums[t] * inv;
        float var = sums[128 + t] * inv - mu * mu;
        float rs = rsqrtf(fmaxf(var, 0.f) + 1e-5f);
        float a = g[t] * rs;
        as_[t] = a;
        bs_[t] = bt[t] - a * mu;
    }
    __syncthreads();
    int half = t >> 7;                  // waves 0-1 vs 2-3: independent 32-node runs
    int c = t & 127;
    int base = blockIdx.x * 64 + half * 32;
    if (base >= Nn) return;
    int lim = base + 32 < Nn ? base + 32 : Nn;
    int g0 = batch[base];
    float s = 0.f, ncnt = 0.f;
    for (int n = base; n < lim; ++n) {
        int gg = batch[n];              // uniform per half -> broadcast, uniform branch
        if (gg != g0) {
            atomicAdd(&pools[(size_t)g0 * HID + c], s);
            if (c == 0) atomicAdd(&cnt[g0], ncnt);
            s = 0.f; ncnt = 0.f; g0 = gg;
        }
        float v = fmaxf(fmaf(h[(size_t)n * HID + c], as_[c], bs_[c]), 0.f);
        s += v;
        ncnt += 1.f;
    }
    atomicAdd(&pools[(size_t)g0 * HID + c], s);
    if (c == 0) atomicAdd(&cnt[g0], ncnt);
}

__global__ void head_kernel(const float* __restrict__ pools, const float* __restrict__ cnt,
                            const float* __restrict__ Wf1, const float* __restrict__ bf1,
                            const float* __restrict__ Wf2, const float* __restrict__ bf2,
                            float* __restrict__ out, int G)
{
    int g = blockIdx.x;
    int t = threadIdx.x;
    __shared__ float p[128];
    float inv = 1.f / fmaxf(cnt[g], 1.f);
    p[t] = pools[g * 128 + t] * inv;
    p[t + 64] = pools[g * 128 + t + 64] * inv;
    __syncthreads();
    float o = bf1[t];
#pragma unroll 8
    for (int k = 0; k < 128; ++k) o = fmaf(p[k], Wf1[k * 64 + t], o);
    o = fmaxf(o, 0.f);
    float prod = o * Wf2[t];
#pragma unroll
    for (int off = 32; off > 0; off >>= 1) prod += __shfl_down(prod, off);
    if (t == 0) out[g] = prod + bf2[0];
}

extern "C" void kernel_launch(void* const* d_in, const int* in_sizes, int n_in,
                              void* d_out, int out_size, void* d_ws, size_t ws_size,
                              hipStream_t stream)
{
    const float* x     = (const float*)d_in[0];
    const float* ea    = (const float*)d_in[1];
    const int*   eidx  = (const int*)d_in[2];
    const int*   batch = (const int*)d_in[3];
    const float* We1 = (const float*)d_in[4];  const float* be1 = (const float*)d_in[5];
    const float* W11 = (const float*)d_in[6];  const float* b11 = (const float*)d_in[7];
    const float* W12 = (const float*)d_in[8];  const float* b12 = (const float*)d_in[9];
    const float* g1  = (const float*)d_in[10]; const float* bt1 = (const float*)d_in[11];
    const float* We2 = (const float*)d_in[12]; const float* be2 = (const float*)d_in[13];
    const float* W21 = (const float*)d_in[14]; const float* b21 = (const float*)d_in[15];
    const float* W22 = (const float*)d_in[16]; const float* b22 = (const float*)d_in[17];
    const float* g2  = (const float*)d_in[18]; const float* bt2 = (const float*)d_in[19];
    const float* We3 = (const float*)d_in[20]; const float* be3 = (const float*)d_in[21];
    const float* W31 = (const float*)d_in[22]; const float* b31 = (const float*)d_in[23];
    const float* W32 = (const float*)d_in[24]; const float* b32 = (const float*)d_in[25];
    const float* g3  = (const float*)d_in[26]; const float* bt3 = (const float*)d_in[27];
    const float* Wf1 = (const float*)d_in[28]; const float* bf1 = (const float*)d_in[29];
    const float* Wf2 = (const float*)d_in[30]; const float* bf2 = (const float*)d_in[31];

    const int N = in_sizes[0] / 7;
    const int E = in_sizes[1] / 3;
    const int G = out_size;
    const int* src = eidx;
    const int* dst = eidx + E;

    float* ws = (float*)d_ws;
    float* buf_t     = ws;                                   // N*128 (pre-BN output)
    unsigned* aggp   = (unsigned*)(buf_t + (size_t)N * HID); // N*128 packed hi/lo agg
    float* agg7      = (float*)(aggp + (size_t)N * HID);     // N*7
    float* bnsums    = agg7 + (size_t)N * 7;                 // 3 x 256
    float* pools     = bnsums + 768;                         // G*128
    float* cntp      = pools + (size_t)G * HID;              // G
    size_t fused     = (size_t)(cntp + G - ws);
    fused = (fused + 3) & ~(size_t)3;                        // 16B align for epack
    float4* epack    = (float4*)(ws + fused);                // E float4
    unsigned short* h16 = (unsigned short*)(epack + E);      // N*128 bf16
    int*   icnt      = (int*)(h16 + (size_t)N * HID);        // N
    int*   ioffs     = icnt + N;                             // N+1
    int*   ibcur     = ioffs + N + 1;                        // 256 (bucket slice cursors)
    int*   ipart     = ibcur + 256;                          // 256
    int*   iexcl     = ipart + 256;                          // N
    unsigned short* wt = (unsigned short*)(iexcl + N);       // 5 x 2 x 16384
    unsigned short* w12h = wt;            unsigned short* w12l = wt + 16384;
    unsigned short* w21h = wt + 32768;    unsigned short* w21l = wt + 49152;
    unsigned short* w22h = wt + 65536;    unsigned short* w22l = wt + 81920;
    unsigned short* w31h = wt + 98304;    unsigned short* w31l = wt + 114688;
    unsigned short* w32h = wt + 131072;   unsigned short* w32l = wt + 147456;
    // stage buffers for the edge sort alias buf_t (not live until layer 1)
    float4* stage    = (float4*)buf_t;                       // E float4
    int*    sdst     = (int*)(stage + E);                    // E ints (fits: 16MB < 25.6MB)

    const long long NH = (long long)N * HID;
    const int blk = 256;
    const unsigned grid_nh2  = (unsigned)((NH / 2 + blk - 1) / blk);
    const unsigned grid_mfma = (unsigned)((N + 63) / 64);
    const unsigned grid_E    = (unsigned)((E + blk - 1) / blk);
    const unsigned nb_scan   = (unsigned)((N + 255) / 256);
    const unsigned grid_gather = (unsigned)((N + 3) / 4);
    const unsigned grid_gat7 = (unsigned)(((long long)N * 8 + blk - 1) / blk);
    const unsigned grid_pool = (unsigned)((N + 63) / 64);
    const unsigned grid_part = (unsigned)((E + CHUNK - 1) / CHUNK);
    const unsigned grid_buck = (unsigned)((N + 255) / 256);

    // ---------- W splits + bnsums zeroing (one launch) ----------
    wsplit_all<<<321, 256, 0, stream>>>(W12, W21, W22, W31, W32, wt, bnsums);

    // ---------- build CSR with packed edges (LDS-staged sort, coalesced writes) ----------
    hipMemsetAsync(icnt, 0, (size_t)N * sizeof(int), stream);
    hist_kernel<<<grid_E, blk, 0, stream>>>(dst, icnt, E);
    scan_block<<<nb_scan, 256, 0, stream>>>(icnt, iexcl, ipart, N);
    scan_partials<<<1, 256, 0, stream>>>(ipart, nb_scan, ioffs, N, E);
    scan_add<<<nb_scan, 256, 0, stream>>>(iexcl, ipart, ioffs, ibcur, N);
    epart<<<grid_part, 256, 0, stream>>>(dst, src, ea, ibcur, stage, sdst, E);
    elocal<<<grid_buck, 256, 0, stream>>>(stage, sdst, ioffs, epack, N);

    // ---------- layer 1 ----------
    gather_d7<<<grid_gat7, blk, 0, stream>>>(x, epack, ioffs, We1, be1, agg7, N);
    mlp1_fused<false, true><<<grid_mfma, 256, 0, stream>>>(x, agg7, W11, b11, w12h, w12l, b12, buf_t, bnsums, N);
    bn_apply_relu<<<grid_nh2, blk, 0, stream>>>(buf_t, bnsums, g1, bt1, h16, N, NH);

    // ---------- layer 2 ----------
    gather_d128<<<grid_gather, 256, 0, stream>>>(h16, epack, ioffs, We2, be2, aggp, N);
    mlp128_fused<false, true><<<grid_mfma, 256, 0, stream>>>(aggp, w21h, w21l, b21, w22h, w22l, b22, buf_t, bnsums + 256, N);
    bn_apply_relu<<<grid_nh2, blk, 0, stream>>>(buf_t, bnsums + 256, g2, bt2, h16, N, NH);

    // ---------- layer 3 ----------
    gather_d128<<<grid_gather, 256, 0, stream>>>(h16, epack, ioffs, We3, be3, aggp, N);
    mlp128_fused<false, true><<<grid_mfma, 256, 0, stream>>>(aggp, w31h, w31l, b31, w32h, w32l, b32, buf_t, bnsums + 512, N);

    // ---------- fused BN-apply + segmented pool, then head ----------
    hipMemsetAsync(pools, 0, ((size_t)G * HID + G) * sizeof(float), stream);
    bn_pool<<<grid_pool, 256, 0, stream>>>(buf_t, bnsums + 512, g3, bt3, batch, pools, cntp, N);
    head_kernel<<<G, 64, 0, stream>>>(pools, cntp, Wf1, bf1, Wf2, bf2, (float*)d_out, G);
}

// Round 4
// 428.126 us; speedup vs baseline: 1.2475x; 1.0474x over previous
//
#include <hip/hip_runtime.h>

#define HID 128
#define CHUNK 3072      // edges per epart block
#define CAP2 5120       // max edges per 256-node bucket in elocal fast path

typedef __attribute__((ext_vector_type(8))) short bf16x8;
typedef __attribute__((ext_vector_type(4))) float f32x4;

__device__ inline unsigned short f2bf(float f) {
    unsigned u = __float_as_uint(f);
    unsigned r = (u + 0x7fff + ((u >> 16) & 1)) >> 16;
    return (unsigned short)r;
}
__device__ inline float bf2f(unsigned short b) {
    return __uint_as_float(((unsigned)b) << 16);
}
// split v into trunc-bf16 hi (low 16 bits) + trunc-bf16 lo (high 16 bits)
__device__ inline unsigned packhl(float v) {
    unsigned h = __float_as_uint(v) >> 16;
    float lo = v - __uint_as_float(h << 16);
    unsigned l = __float_as_uint(lo) >> 16;
    return h | (l << 16);
}

// ===== fused preamble: W hi/lo splits + bnsums/pools zero + dst histogram =====
__global__ __launch_bounds__(256) void fused_pre(
    const float* __restrict__ W12, const float* __restrict__ W21,
    const float* __restrict__ W22, const float* __restrict__ W31,
    const float* __restrict__ W32, unsigned short* __restrict__ wt,
    float* __restrict__ bnsums, float* __restrict__ poolz, long long PZ,
    const int* __restrict__ dst, int* __restrict__ icnt, int E)
{
    int b = blockIdx.x, t = threadIdx.x;
    if (b < 320) {
        int w = b >> 6;
        int idx = (b & 63) * 256 + t;
        const float* W = (w == 0) ? W12 : (w == 1) ? W21 : (w == 2) ? W22 : (w == 3) ? W31 : W32;
        unsigned short* wh = wt + (size_t)w * 32768;
        unsigned short* wl = wh + 16384;
        int n = idx >> 7, k = idx & 127;
        float wv = W[k * 128 + n];
        unsigned short h = (unsigned short)(__float_as_uint(wv) >> 16);
        float lo = wv - bf2f(h);
        unsigned short l = (unsigned short)(__float_as_uint(lo) >> 16);
        wh[idx] = h;
        wl[idx] = l;
    } else if (b == 320) {
        for (int i = t; i < 768; i += 256) bnsums[i] = 0.f;
    } else if (b < 338) {
        long long s0 = (long long)(b - 321) * 16384;
        long long e1 = s0 + 16384; if (e1 > PZ) e1 = PZ;
        for (long long i = s0 + t; i < e1; i += 256) poolz[i] = 0.f;
    } else {
        int stride = (gridDim.x - 338) * 256;
        for (int e = (b - 338) * 256 + t; e < E; e += stride)
            atomicAdd(&icnt[dst[e]], 1);
    }
}

// ================= CSR scan =================
__global__ void scan_block(const int* __restrict__ cnt, int* __restrict__ excl,
                           int* __restrict__ partials, int Nn)
{
    __shared__ int ls[256];
    int i = blockIdx.x * 256 + threadIdx.x;
    int v = (i < Nn) ? cnt[i] : 0;
    ls[threadIdx.x] = v;
    __syncthreads();
    for (int off = 1; off < 256; off <<= 1) {
        int t = (threadIdx.x >= off) ? ls[threadIdx.x - off] : 0;
        __syncthreads();
        ls[threadIdx.x] += t;
        __syncthreads();
    }
    if (i < Nn) excl[i] = ls[threadIdx.x] - v;
    if (threadIdx.x == 255) partials[blockIdx.x] = ls[255];
}

// per-block redundant partials scan + offsets/bcur write (replaces 2 kernels)
__global__ void scan_addf(const int* __restrict__ excl, const int* __restrict__ partials,
                          int nb, int* __restrict__ offsets, int* __restrict__ bcur,
                          int Nn, int E)
{
    __shared__ int ls[256];
    int t = threadIdx.x;
    int v = (t < nb) ? partials[t] : 0;
    ls[t] = v;
    __syncthreads();
    for (int off = 1; off < 256; off <<= 1) {
        int x = (t >= off) ? ls[t - off] : 0;
        __syncthreads();
        ls[t] += x;
        __syncthreads();
    }
    int base = (blockIdx.x > 0) ? ls[blockIdx.x - 1] : 0;
    int i = blockIdx.x * 256 + t;
    if (i < Nn) {
        int o = excl[i] + base;
        offsets[i] = o;
        if ((i & 255) == 0) bcur[i >> 8] = o;
    }
    if (blockIdx.x == 0 && t == 0) offsets[Nn] = E;
}

// ===== epart: partition edges into 256-node MSD buckets (index-staged, LDS-light) =====
__global__ __launch_bounds__(256) void epart(
    const int* __restrict__ dst, const int* __restrict__ src,
    const float* __restrict__ ea, int* __restrict__ bcur,
    float4* __restrict__ stage, int* __restrict__ sdst, int E)
{
    __shared__ int dl[CHUNK];              // 12KB: dst value per original k
    __shared__ unsigned short idxl[CHUNK]; // 6KB: original k per sorted slot
    __shared__ int cnt[256], gsl[256], exs[256], scw[256];
    int t = threadIdx.x;
    int e0 = blockIdx.x * CHUNK;
    int n = E - e0; if (n > CHUNK) n = CHUNK;
    cnt[t] = 0;
    __syncthreads();
    for (int k = t; k < n; k += 256) {
        int dv = dst[e0 + k];
        dl[k] = dv;
        atomicAdd(&cnt[dv >> 8], 1);
    }
    __syncthreads();
    int v = cnt[t];
    int gb = 0;
    if (v > 0) gb = atomicAdd(&bcur[t], v);
    gsl[t] = gb;
    scw[t] = v;
    __syncthreads();
    for (int off = 1; off < 256; off <<= 1) {
        int x = (t >= off) ? scw[t - off] : 0;
        __syncthreads();
        scw[t] += x;
        __syncthreads();
    }
    int excl = scw[t] - v;
    exs[t] = excl;
    cnt[t] = excl;              // fill cursor
    __syncthreads();
    for (int k = t; k < n; k += 256) {
        int d = dl[k] >> 8;
        int s = atomicAdd(&cnt[d], 1);
        idxl[s] = (unsigned short)k;
    }
    __syncthreads();
    // writeout: consecutive slots -> consecutive stage addresses per bucket run
    for (int k = t; k < n; k += 256) {
        int kk = idxl[k];
        int dv = dl[kk];
        int d = dv >> 8;
        int pos = gsl[d] + (k - exs[d]);
        int e = e0 + kk;
        float4 p;
        p.x = __int_as_float(src[e]);
        p.y = ea[e * 3];
        p.z = ea[e * 3 + 1];
        p.w = ea[e * 3 + 2];
        stage[pos] = p;
        sdst[pos] = dv;
    }
}

// ===== elocal: per-bucket counting sort into final CSR epack (index-staged) =====
__global__ __launch_bounds__(256) void elocal(
    const float4* __restrict__ stage, const int* __restrict__ sdst,
    const int* __restrict__ offsets, float4* __restrict__ epack, int Nn)
{
    __shared__ unsigned short idxl[CAP2];  // 10KB
    __shared__ unsigned char  ldc[CAP2];   // 5KB: local dst (0..255)
    __shared__ int cnt[256], exs[256], noff[256], scw[256];
    int t = threadIdx.x;
    int b = blockIdx.x;
    int nbeg = b << 8;
    int nend = nbeg + 256; if (nend > Nn) nend = Nn;
    int beg = offsets[nbeg];
    int end = offsets[nend];
    int n = end - beg;
    noff[t] = (nbeg + t < Nn) ? offsets[nbeg + t] : 0;
    cnt[t] = 0;
    __syncthreads();
    if (n <= CAP2) {
        for (int k = t; k < n; k += 256) {
            int d = sdst[beg + k] & 255;
            ldc[k] = (unsigned char)d;
            atomicAdd(&cnt[d], 1);
        }
        __syncthreads();
        int v = cnt[t];
        scw[t] = v;
        __syncthreads();
        for (int off = 1; off < 256; off <<= 1) {
            int x = (t >= off) ? scw[t - off] : 0;
            __syncthreads();
            scw[t] += x;
            __syncthreads();
        }
        int excl = scw[t] - v;
        exs[t] = excl;
        cnt[t] = excl;          // fill cursor
        __syncthreads();
        for (int k = t; k < n; k += 256) {
            int d = ldc[k];
            int s = atomicAdd(&cnt[d], 1);
            idxl[s] = (unsigned short)k;
        }
        __syncthreads();
        for (int k = t; k < n; k += 256) {
            int kk = idxl[k];
            int d = ldc[kk];
            int pos = noff[d] + (k - exs[d]);
            epack[pos] = stage[beg + kk];   // gathered read (L2-hot), linear-run write
        }
    } else {
        for (int k = t; k < n; k += 256) {
            int d = sdst[beg + k] & 255;
            int r = atomicAdd(&cnt[d], 1);
            epack[noff[d] + r] = stage[beg + k];
        }
    }
}

// ====== layers 2/3: gather with inline BN+ReLU of h16 (pre-BN bf16) ======
__global__ __launch_bounds__(256) void gather_d128(
    const unsigned short* __restrict__ h16,
    const float4* __restrict__ epack,
    const int* __restrict__ offsets,
    const float* __restrict__ We, const float* __restrict__ be,
    const float* __restrict__ sums, const float* __restrict__ g,
    const float* __restrict__ bt,
    unsigned* __restrict__ aggp, int Nn)
{
    __shared__ float as_[128], bs_[128];
    int t = threadIdx.x;
    if (t < 128) {
        float inv = 1.f / (float)Nn;
        float mu = sums[t] * inv;
        float var = sums[128 + t] * inv - mu * mu;
        float rs = rsqrtf(fmaxf(var, 0.f) + 1e-5f);
        float a = g[t] * rs;
        as_[t] = a;
        bs_[t] = bt[t] - a * mu;
    }
    __syncthreads();
    int node = blockIdx.x * 4 + (t >> 6);
    if (node >= Nn) return;
    int lane = t & 63;
    int beg = __builtin_amdgcn_readfirstlane(offsets[node]);
    int end = __builtin_amdgcn_readfirstlane(offsets[node + 1]);
    const float2* W2 = (const float2*)We;
    float2 w0 = W2[lane];
    float2 w1 = W2[64 + lane];
    float2 w2 = W2[128 + lane];
    float2 bb = ((const float2*)be)[lane];
    float2 aa = ((const float2*)as_)[lane];
    float2 ab = ((const float2*)bs_)[lane];
    float accx = 0.f, accy = 0.f;

    int i = beg;
    for (; i + 8 <= end; i += 8) {
        float4 e[8];
        ushort2 p[8];
#pragma unroll
        for (int j = 0; j < 8; ++j) e[j] = epack[i + j];
#pragma unroll
        for (int j = 0; j < 8; ++j)
            p[j] = ((const ushort2*)(h16 + (size_t)__float_as_int(e[j].x) * HID))[lane];
#pragma unroll
        for (int j = 0; j < 8; ++j) {
            float hx = fmaxf(fmaf(bf2f(p[j].x), aa.x, ab.x), 0.f);
            float hy = fmaxf(fmaf(bf2f(p[j].y), aa.y, ab.y), 0.f);
            float vx = bb.x + hx;
            vx = fmaf(e[j].y, w0.x, vx); vx = fmaf(e[j].z, w1.x, vx); vx = fmaf(e[j].w, w2.x, vx);
            float vy = bb.y + hy;
            vy = fmaf(e[j].y, w0.y, vy); vy = fmaf(e[j].z, w1.y, vy); vy = fmaf(e[j].w, w2.y, vy);
            accx += fmaxf(vx, 0.f);
            accy += fmaxf(vy, 0.f);
        }
    }
    int rem = end - i;        // wave-uniform -> cheap s_cbranch predication
    if (rem > 0) {
        float4 e[8];
        ushort2 p[8];
#pragma unroll
        for (int j = 0; j < 8; ++j) if (j < rem) e[j] = epack[i + j];
#pragma unroll
        for (int j = 0; j < 8; ++j) if (j < rem)
            p[j] = ((const ushort2*)(h16 + (size_t)__float_as_int(e[j].x) * HID))[lane];
#pragma unroll
        for (int j = 0; j < 8; ++j) if (j < rem) {
            float hx = fmaxf(fmaf(bf2f(p[j].x), aa.x, ab.x), 0.f);
            float hy = fmaxf(fmaf(bf2f(p[j].y), aa.y, ab.y), 0.f);
            float vx = bb.x + hx;
            vx = fmaf(e[j].y, w0.x, vx); vx = fmaf(e[j].z, w1.x, vx); vx = fmaf(e[j].w, w2.x, vx);
            float vy = bb.y + hy;
            vy = fmaf(e[j].y, w0.y, vy); vy = fmaf(e[j].z, w1.y, vy); vy = fmaf(e[j].w, w2.y, vy);
            accx += fmaxf(vx, 0.f);
            accy += fmaxf(vy, 0.f);
        }
    }
    // self term: BN+relu of own pre-BN row
    ushort2 hv = ((const ushort2*)(h16 + (size_t)node * HID))[lane];
    float sx = fmaxf(fmaf(bf2f(hv.x), aa.x, ab.x), 0.f);
    float sy = fmaxf(fmaf(bf2f(hv.y), aa.y, ab.y), 0.f);
    uint2 ov;
    ov.x = packhl(accx + sx);
    ov.y = packhl(accy + sy);
    ((uint2*)(aggp + (size_t)node * HID))[lane] = ov;
}

// ===== unpack interleaved hi/lo uint pairs into two bf16x8 via v_perm_b32 =====
__device__ __forceinline__ void unpack_hl(const unsigned* Tp, bf16x8& ah, bf16x8& al)
{
    uint4 pa = *(const uint4*)Tp;
    uint4 pb = *(const uint4*)(Tp + 4);
    union { unsigned u[4]; bf16x8 v; } H, L;
    H.u[0] = __builtin_amdgcn_perm(pa.y, pa.x, 0x05040100u);
    L.u[0] = __builtin_amdgcn_perm(pa.y, pa.x, 0x07060302u);
    H.u[1] = __builtin_amdgcn_perm(pa.w, pa.z, 0x05040100u);
    L.u[1] = __builtin_amdgcn_perm(pa.w, pa.z, 0x07060302u);
    H.u[2] = __builtin_amdgcn_perm(pb.y, pb.x, 0x05040100u);
    L.u[2] = __builtin_amdgcn_perm(pb.y, pb.x, 0x07060302u);
    H.u[3] = __builtin_amdgcn_perm(pb.w, pb.z, 0x05040100u);
    L.u[3] = __builtin_amdgcn_perm(pb.w, pb.z, 0x07060302u);
    ah = H.v;
    al = L.v;
}

// ===== MFMA core: acc[2][4] = T(64 rows packed hi/lo) @ Wt for this wave's 32 cols =====
__device__ __forceinline__ void mfma_core(
    const unsigned* T,
    const unsigned short* __restrict__ Wh, const unsigned short* __restrict__ Wl,
    const float* __restrict__ bias,
    int wave, int q, int li, f32x4 (&acc)[2][4])
{
    int ctg0 = wave * 2, ctg1 = wave * 2 + 1;
    float b0 = bias[ctg0 * 16 + li];
    float b1v = bias[ctg1 * 16 + li];
#pragma unroll
    for (int rf = 0; rf < 4; ++rf) {
        acc[0][rf][0] = b0;  acc[0][rf][1] = b0;  acc[0][rf][2] = b0;  acc[0][rf][3] = b0;
        acc[1][rf][0] = b1v; acc[1][rf][1] = b1v; acc[1][rf][2] = b1v; acc[1][rf][3] = b1v;
    }
#pragma unroll
    for (int kb = 0; kb < 4; ++kb) {
        int k0 = kb * 32 + q * 8;
        size_t w0off = (size_t)(ctg0 * 16 + li) * HID + k0;
        size_t w1off = (size_t)(ctg1 * 16 + li) * HID + k0;
        bf16x8 bh0 = *(const bf16x8*)(Wh + w0off);
        bf16x8 bl0 = *(const bf16x8*)(Wl + w0off);
        bf16x8 bh1 = *(const bf16x8*)(Wh + w1off);
        bf16x8 bl1 = *(const bf16x8*)(Wl + w1off);
#pragma unroll
        for (int rf = 0; rf < 4; ++rf) {
            const unsigned* Tp = T + (rf * 16 + li) * 132 + k0;
            bf16x8 ah, al;
            unpack_hl(Tp, ah, al);
            acc[0][rf] = __builtin_amdgcn_mfma_f32_16x16x32_bf16(ah, bh0, acc[0][rf], 0, 0, 0);
            acc[0][rf] = __builtin_amdgcn_mfma_f32_16x16x32_bf16(ah, bl0, acc[0][rf], 0, 0, 0);
            acc[0][rf] = __builtin_amdgcn_mfma_f32_16x16x32_bf16(al, bh0, acc[0][rf], 0, 0, 0);
            acc[1][rf] = __builtin_amdgcn_mfma_f32_16x16x32_bf16(ah, bh1, acc[1][rf], 0, 0, 0);
            acc[1][rf] = __builtin_amdgcn_mfma_f32_16x16x32_bf16(ah, bl1, acc[1][rf], 0, 0, 0);
            acc[1][rf] = __builtin_amdgcn_mfma_f32_16x16x32_bf16(al, bh1, acc[1][rf], 0, 0, 0);
        }
    }
}

// epilogue: h (pre-BN) -> bf16 via LDS bounce (coalesced), BN stats to bnsums
__device__ __forceinline__ void epilogue_h16(
    f32x4 (&acc)[2][4], unsigned short* __restrict__ h16g,
    float* __restrict__ bnsums, float* sls, float* slq, unsigned short* Th,
    int node0, int wave, int q, int li, int t, int N)
{
#pragma unroll
    for (int ct = 0; ct < 2; ++ct) {
        int colb = (wave * 2 + ct) * 16 + li;
        float sv = 0.f, qv = 0.f;
#pragma unroll
        for (int rf = 0; rf < 4; ++rf) {
#pragma unroll
            for (int r = 0; r < 4; ++r) {
                int rloc = rf * 16 + q * 4 + r;
                float v = acc[ct][rf][r];
                Th[rloc * 128 + colb] = f2bf(v);
                if (node0 + rloc < N) { sv += v; qv = fmaf(v, v, qv); }
            }
        }
        sv += __shfl_down(sv, 16); sv += __shfl_down(sv, 32);
        qv += __shfl_down(qv, 16); qv += __shfl_down(qv, 32);
        if (q == 0) { sls[colb] = sv; slq[colb] = qv; }
    }
    __syncthreads();
    int rows = N - node0; if (rows > 64) rows = 64;
    uint4* dstp = (uint4*)(h16g + (size_t)node0 * HID);
    const uint4* srcp = (const uint4*)Th;
    for (int i = t; i < rows * 16; i += 256) dstp[i] = srcp[i];
    if (t < 128) {
        atomicAdd(&bnsums[t], sls[t]);
        atomicAdd(&bnsums[128 + t], slq[t]);
    }
}

// ===== fused MLP layers 2/3: h16 = bf16(Lin2(relu(Lin1(A)))), stats fused =====
__global__ __launch_bounds__(256) void mlp128_fused(
    const unsigned* __restrict__ Ap,
    const unsigned short* __restrict__ W1h, const unsigned short* __restrict__ W1l,
    const float* __restrict__ b1,
    const unsigned short* __restrict__ W2h, const unsigned short* __restrict__ W2l,
    const float* __restrict__ b2,
    unsigned short* __restrict__ h16g, float* __restrict__ bnsums, int N)
{
    __shared__ unsigned Ta[64 * 132];
    __shared__ unsigned Tb[64 * 132];
    __shared__ float sls[128], slq[128];
    int t = threadIdx.x;
    int wave = t >> 6, lane = t & 63;
    int q = lane >> 4, li = lane & 15;
    int node0 = blockIdx.x * 64;

    // ---- stage A (already packed): straight uint4 copy global -> padded LDS ----
    {
        const uint4* A4 = (const uint4*)(Ap + (size_t)node0 * HID);
        int rows = N - node0 < 64 ? (N - node0) : 64;
        int limit4 = 32 * rows;
#pragma unroll
        for (int i = 0; i < 8; ++i) {
            int idx = t + i * 256;
            uint4 v = {0u, 0u, 0u, 0u};
            if (idx < limit4) v = A4[idx];
            int row = idx >> 5, c4 = idx & 31;
            *(uint4*)(Ta + row * 132 + c4 * 4) = v;
        }
    }
    __syncthreads();

    // ---- phase 1: Ta @ W1 -> relu -> packed Tb ----
    {
        f32x4 acc[2][4];
        mfma_core(Ta, W1h, W1l, b1, wave, q, li, acc);
#pragma unroll
        for (int ct = 0; ct < 2; ++ct) {
            int colb = (wave * 2 + ct) * 16 + li;
#pragma unroll
            for (int rf = 0; rf < 4; ++rf) {
#pragma unroll
                for (int r = 0; r < 4; ++r) {
                    float v = fmaxf(acc[ct][rf][r], 0.f);
                    Tb[(rf * 16 + q * 4 + r) * 132 + colb] = packhl(v);
                }
            }
        }
    }
    __syncthreads();

    // ---- phase 2: Tb @ W2 -> h16 (+stats); Ta reused as bf16 bounce buffer ----
    {
        f32x4 acc[2][4];
        mfma_core(Tb, W2h, W2l, b2, wave, q, li, acc);
        epilogue_h16(acc, h16g, bnsums, sls, slq, (unsigned short*)Ta,
                     node0, wave, q, li, t, N);
    }
}

// ===== fused MLP layer 1: phase-0 d7 CSR gather, phase-1 K=7 fp32, phase-2 MFMA =====
__global__ __launch_bounds__(256) void mlp1_fused(
    const float* __restrict__ x, const float4* __restrict__ epack,
    const int* __restrict__ offsets,
    const float* __restrict__ We, const float* __restrict__ be,   // 3x7, 7
    const float* __restrict__ W1, const float* __restrict__ b1,   // [7][128]
    const unsigned short* __restrict__ W2h, const unsigned short* __restrict__ W2l,
    const float* __restrict__ b2,
    unsigned short* __restrict__ h16g, float* __restrict__ bnsums, int N)
{
    __shared__ unsigned Tb[64 * 132];
    __shared__ unsigned short Th[64 * 128];
    __shared__ float ls_agg[64][8];
    __shared__ float sls[128], slq[128];
    int t = threadIdx.x;
    int wave = t >> 6, lane = t & 63;
    int q = lane >> 4, li = lane & 15;
    int node0 = blockIdx.x * 64;

    // ---- phase 0: d7 gather; wave w owns rows w*16..w*16+15, 4 lanes per row ----
    {
        int rl = lane >> 2, qq = lane & 3;
        int lrow = wave * 16 + rl;
        int row = node0 + lrow;
        bool okr = row < N;
        int c0 = qq * 2;
        bool has1 = qq < 3;
        float w00 = We[c0], w10 = We[7 + c0], w20 = We[14 + c0], be0 = be[c0];
        float w01 = has1 ? We[c0 + 1] : 0.f, w11 = has1 ? We[8 + c0] : 0.f;
        float w21 = has1 ? We[15 + c0] : 0.f, be1v = has1 ? be[c0 + 1] : 0.f;
        int beg = okr ? offsets[row] : 0;
        int end = okr ? offsets[row + 1] : 0;
        float a0 = 0.f, a1 = 0.f;
        for (int i = beg; i < end; i += 4) {
            float4 ep[4]; float x0[4], x1[4];
#pragma unroll
            for (int j = 0; j < 4; ++j) if (i + j < end) ep[j] = epack[i + j];
#pragma unroll
            for (int j = 0; j < 4; ++j) if (i + j < end) {
                int s = __float_as_int(ep[j].x);
                x0[j] = x[s * 7 + c0];
                x1[j] = has1 ? x[s * 7 + c0 + 1] : 0.f;
            }
#pragma unroll
            for (int j = 0; j < 4; ++j) if (i + j < end) {
                float v0 = be0 + x0[j];
                v0 = fmaf(ep[j].y, w00, v0); v0 = fmaf(ep[j].z, w10, v0); v0 = fmaf(ep[j].w, w20, v0);
                a0 += fmaxf(v0, 0.f);
                float v1 = be1v + x1[j];
                v1 = fmaf(ep[j].y, w01, v1); v1 = fmaf(ep[j].z, w11, v1); v1 = fmaf(ep[j].w, w21, v1);
                a1 += fmaxf(v1, 0.f);
            }
        }
        // xa = x_self + agg  (GINE h input)
        ls_agg[lrow][c0] = okr ? (a0 + x[row * 7 + c0]) : 0.f;
        if (has1) ls_agg[lrow][c0 + 1] = okr ? (a1 + x[row * 7 + c0 + 1]) : 0.f;
        else      ls_agg[lrow][7] = 0.f;
    }
    __syncthreads();

    // ---- phase 1: rows wave*16+li, q covers col-groups of 32 ----
    {
        int lrow = wave * 16 + li;
        float xa[7];
#pragma unroll
        for (int k = 0; k < 7; ++k) xa[k] = ls_agg[lrow][k];
        const float4* W14 = (const float4*)W1;
        const float4* b14 = (const float4*)b1;
        unsigned* Trow = Tb + lrow * 132 + q * 32;
#pragma unroll
        for (int c4 = 0; c4 < 8; ++c4) {
            float4 v = b14[q * 8 + c4];
#pragma unroll
            for (int k = 0; k < 7; ++k) {
                float4 w = W14[k * 32 + q * 8 + c4];
                v.x = fmaf(xa[k], w.x, v.x);
                v.y = fmaf(xa[k], w.y, v.y);
                v.z = fmaf(xa[k], w.z, v.z);
                v.w = fmaf(xa[k], w.w, v.w);
            }
            uint4 pk;
            pk.x = packhl(fmaxf(v.x, 0.f));
            pk.y = packhl(fmaxf(v.y, 0.f));
            pk.z = packhl(fmaxf(v.z, 0.f));
            pk.w = packhl(fmaxf(v.w, 0.f));
            *(uint4*)(Trow + c4 * 4) = pk;
        }
    }
    __syncthreads();

    // ---- phase 2 ----
    {
        f32x4 acc[2][4];
        mfma_core(Tb, W2h, W2l, b2, wave, q, li, acc);
        epilogue_h16(acc, h16g, bnsums, sls, slq, Th, node0, wave, q, li, t, N);
    }
}

// ===== layer-3 BN-apply + mean-pool from bf16 h16 (batch sorted, segmented) =====
__global__ __launch_bounds__(256) void bn_pool(
    const unsigned short* __restrict__ h16, const float* __restrict__ sums,
    const float* __restrict__ g, const float* __restrict__ bt,
    const int* __restrict__ batch,
    float* __restrict__ pools, float* __restrict__ cnt, int Nn)
{
    __shared__ float as_[128], bs_[128];
    int t = threadIdx.x;
    if (t < 128) {
        float inv = 1.f / (float)Nn;
        float mu = sums[t] * inv;
        float var = sums[128 + t] * inv - mu * mu;
        float rs = rsqrtf(fmaxf(var, 0.f) + 1e-5f);
        float a = g[t] * rs;
        as_[t] = a;
        bs_[t] = bt[t] - a * mu;
    }
    __syncthreads();
    int half = t >> 7;
    int c = t & 127;
    int base = blockIdx.x * 64 + half * 32;
    if (base >= Nn) return;
    int lim = base + 32 < Nn ? base + 32 : Nn;
    int g0 = batch[base];
    float s = 0.f, ncnt = 0.f;
    for (int n = base; n < lim; ++n) {
        int gg = batch[n];
        if (gg != g0) {
            atomicAdd(&pools[(size_t)g0 * HID + c], s);
            if (c == 0) atomicAdd(&cnt[g0], ncnt);
            s = 0.f; ncnt = 0.f; g0 = gg;
        }
        float hraw = bf2f(h16[(size_t)n * HID + c]);
        float v = fmaxf(fmaf(hraw, as_[c], bs_[c]), 0.f);
        s += v;
        ncnt += 1.f;
    }
    atomicAdd(&pools[(size_t)g0 * HID + c], s);
    if (c == 0) atomicAdd(&cnt[g0], ncnt);
}

__global__ void head_kernel(const float* __restrict__ pools, const float* __restrict__ cnt,
                            const float* __restrict__ Wf1, const float* __restrict__ bf1,
                            const float* __restrict__ Wf2, const float* __restrict__ bf2,
                            float* __restrict__ out, int G)
{
    int g = blockIdx.x;
    int t = threadIdx.x;
    __shared__ float p[128];
    float inv = 1.f / fmaxf(cnt[g], 1.f);
    p[t] = pools[g * 128 + t] * inv;
    p[t + 64] = pools[g * 128 + t + 64] * inv;
    __syncthreads();
    float o = bf1[t];
#pragma unroll 8
    for (int k = 0; k < 128; ++k) o = fmaf(p[k], Wf1[k * 64 + t], o);
    o = fmaxf(o, 0.f);
    float prod = o * Wf2[t];
#pragma unroll
    for (int off = 32; off > 0; off >>= 1) prod += __shfl_down(prod, off);
    if (t == 0) out[g] = prod + bf2[0];
}

extern "C" void kernel_launch(void* const* d_in, const int* in_sizes, int n_in,
                              void* d_out, int out_size, void* d_ws, size_t ws_size,
                              hipStream_t stream)
{
    const float* x     = (const float*)d_in[0];
    const float* ea    = (const float*)d_in[1];
    const int*   eidx  = (const int*)d_in[2];
    const int*   batch = (const int*)d_in[3];
    const float* We1 = (const float*)d_in[4];  const float* be1 = (const float*)d_in[5];
    const float* W11 = (const float*)d_in[6];  const float* b11 = (const float*)d_in[7];
    const float* W12 = (const float*)d_in[8];  const float* b12 = (const float*)d_in[9];
    const float* g1  = (const float*)d_in[10]; const float* bt1 = (const float*)d_in[11];
    const float* We2 = (const float*)d_in[12]; const float* be2 = (const float*)d_in[13];
    const float* W21 = (const float*)d_in[14]; const float* b21 = (const float*)d_in[15];
    const float* W22 = (const float*)d_in[16]; const float* b22 = (const float*)d_in[17];
    const float* g2  = (const float*)d_in[18]; const float* bt2 = (const float*)d_in[19];
    const float* We3 = (const float*)d_in[20]; const float* be3 = (const float*)d_in[21];
    const float* W31 = (const float*)d_in[22]; const float* b31 = (const float*)d_in[23];
    const float* W32 = (const float*)d_in[24]; const float* b32 = (const float*)d_in[25];
    const float* g3  = (const float*)d_in[26]; const float* bt3 = (const float*)d_in[27];
    const float* Wf1 = (const float*)d_in[28]; const float* bf1 = (const float*)d_in[29];
    const float* Wf2 = (const float*)d_in[30]; const float* bf2 = (const float*)d_in[31];

    const int N = in_sizes[0] / 7;
    const int E = in_sizes[1] / 3;
    const int G = out_size;
    const int* src = eidx;
    const int* dst = eidx + E;

    float* ws = (float*)d_ws;
    float4* stage    = (float4*)ws;                          // E float4 (sort staging)
    int*    sdst     = (int*)(stage + E);                    // E ints
    unsigned* aggp   = (unsigned*)(sdst + E);                // N*128 packed hi/lo agg
    float* bnsums    = (float*)(aggp + (size_t)N * HID);     // 3 x 256
    float* pools     = bnsums + 768;                         // G*128
    float* cntp      = pools + (size_t)G * HID;              // G
    size_t fused     = (size_t)(cntp + G - ws);
    fused = (fused + 3) & ~(size_t)3;                        // 16B align for epack
    float4* epack    = (float4*)(ws + fused);                // E float4
    unsigned short* h16 = (unsigned short*)(epack + E);      // N*128 bf16 (pre-BN h)
    int*   icnt      = (int*)(h16 + (size_t)N * HID);        // N
    int*   ioffs     = icnt + N;                             // N+1
    int*   ibcur     = ioffs + N + 1;                        // 256 (bucket slice cursors)
    int*   ipart     = ibcur + 256;                          // 256
    int*   iexcl     = ipart + 256;                          // N
    unsigned short* wt = (unsigned short*)(iexcl + N);       // 5 x 2 x 16384
    unsigned short* w12h = wt;            unsigned short* w12l = wt + 16384;
    unsigned short* w21h = wt + 32768;    unsigned short* w21l = wt + 49152;
    unsigned short* w22h = wt + 65536;    unsigned short* w22l = wt + 81920;
    unsigned short* w31h = wt + 98304;    unsigned short* w31l = wt + 114688;
    unsigned short* w32h = wt + 131072;   unsigned short* w32l = wt + 147456;

    const unsigned grid_mfma = (unsigned)((N + 63) / 64);
    const unsigned nb_scan   = (unsigned)((N + 255) / 256);
    const unsigned grid_gather = (unsigned)((N + 3) / 4);
    const unsigned grid_pool = (unsigned)((N + 63) / 64);
    const unsigned grid_part = (unsigned)((E + CHUNK - 1) / CHUNK);
    const unsigned grid_buck = (unsigned)((N + 255) / 256);
    const long long PZ = (long long)G * HID + G;

    // ---------- preamble: W splits + zeros + histogram (one launch) ----------
    hipMemsetAsync(icnt, 0, (size_t)N * sizeof(int), stream);
    fused_pre<<<1122, 256, 0, stream>>>(W12, W21, W22, W31, W32, wt,
                                        bnsums, pools, PZ, dst, icnt, E);

    // ---------- CSR offsets + two-phase edge sort ----------
    scan_block<<<nb_scan, 256, 0, stream>>>(icnt, iexcl, ipart, N);
    scan_addf<<<nb_scan, 256, 0, stream>>>(iexcl, ipart, (int)nb_scan, ioffs, ibcur, N, E);
    epart<<<grid_part, 256, 0, stream>>>(dst, src, ea, ibcur, stage, sdst, E);
    elocal<<<grid_buck, 256, 0, stream>>>(stage, sdst, ioffs, epack, N);

    // ---------- layer 1 (d7 gather fused into MLP) ----------
    mlp1_fused<<<grid_mfma, 256, 0, stream>>>(x, epack, ioffs, We1, be1,
                                              W11, b11, w12h, w12l, b12,
                                              h16, bnsums, N);

    // ---------- layer 2 ----------
    gather_d128<<<grid_gather, 256, 0, stream>>>(h16, epack, ioffs, We2, be2,
                                                 bnsums, g1, bt1, aggp, N);
    mlp128_fused<<<grid_mfma, 256, 0, stream>>>(aggp, w21h, w21l, b21, w22h, w22l, b22,
                                                h16, bnsums + 256, N);

    // ---------- layer 3 ----------
    gather_d128<<<grid_gather, 256, 0, stream>>>(h16, epack, ioffs, We3, be3,
                                                 bnsums + 256, g2, bt2, aggp, N);
    mlp128_fused<<<grid_mfma, 256, 0, stream>>>(aggp, w31h, w31l, b31, w32h, w32l, b32,
                                                h16, bnsums + 512, N);

    // ---------- BN-apply + segmented pool + head ----------
    bn_pool<<<grid_pool, 256, 0, stream>>>(h16, bnsums + 512, g3, bt3, batch,
                                           pools, cntp, N);
    head_kernel<<<G, 64, 0, stream>>>(pools, cntp, Wf1, bf1, Wf2, bf2, (float*)d_out, G);
}